// Round 1
// baseline (666.589 us; speedup 1.0000x reference)
//
#include <hip/hip_runtime.h>

#define HID 256

// ---------------- degree count ----------------
__global__ void k_count(const int* __restrict__ dst, int* __restrict__ cnt, int E) {
    for (int i = blockIdx.x * blockDim.x + threadIdx.x; i < E; i += gridDim.x * blockDim.x)
        atomicAdd(&cnt[dst[i]], 1);
}

// dis[v] = rsqrt(deg) with deg = cnt + 1 (self loop)
__global__ void k_dis(const int* __restrict__ cnt, float* __restrict__ dis, int n) {
    int i = blockIdx.x * blockDim.x + threadIdx.x;
    if (i < n) dis[i] = rsqrtf((float)(cnt[i] + 1));
}

// ---------------- exclusive scan (single block, 256 threads) ----------------
__global__ void k_scan(const int* __restrict__ cnt, int* __restrict__ off, int n) {
    __shared__ int s[256];
    int t = threadIdx.x;
    int C = (n + 255) / 256;
    int lo = t * C, hi = min(lo + C, n);
    int sum = 0;
    for (int i = lo; i < hi; ++i) sum += cnt[i];
    s[t] = sum;
    __syncthreads();
    for (int d = 1; d < 256; d <<= 1) {
        int v = (t >= d) ? s[t - d] : 0;
        __syncthreads();
        s[t] += v;
        __syncthreads();
    }
    int run = s[t] - sum;  // exclusive prefix
    for (int i = lo; i < hi; ++i) { off[i] = run; run += cnt[i]; }
    if (t == 255) off[n] = s[255];
}

// ---------------- CSR fill (by dst) ----------------
__global__ void k_fill(const int* __restrict__ src, const int* __restrict__ dst,
                       const int* __restrict__ off, int* __restrict__ fill,
                       int* __restrict__ csr, int E) {
    for (int i = blockIdx.x * blockDim.x + threadIdx.x; i < E; i += gridDim.x * blockDim.x) {
        int d = dst[i];
        int pos = off[d] + atomicAdd(&fill[d], 1);
        csr[pos] = src[i];
    }
}

// ---------------- GEMM: Y = (X @ W) * dis[row], also copied to Acc (self-loop init) ----
// X: [M,K] row-major, W: [K,256] row-major. Block = 64 rows x 256 cols, 256 threads,
// each thread 8x8 outputs. BK=32.
template <int K>
__global__ __launch_bounds__(256) void k_gemm(const float* __restrict__ X,
                                              const float* __restrict__ W,
                                              const float* __restrict__ dis,
                                              float* __restrict__ Y,
                                              float* __restrict__ Acc, int M) {
    __shared__ float As[64][33];
    __shared__ float Ws[32][256];
    const int tid = threadIdx.x;
    const int row0 = blockIdx.x * 64;
    const int n0 = (tid & 31) * 8;
    const int m0 = (tid >> 5) * 8;
    float acc[8][8];
#pragma unroll
    for (int i = 0; i < 8; ++i)
#pragma unroll
        for (int j = 0; j < 8; ++j) acc[i][j] = 0.f;

    for (int k0 = 0; k0 < K; k0 += 32) {
#pragma unroll
        for (int i = 0; i < 2; ++i) {
            int f4 = tid + i * 256;
            int r = f4 >> 3, c = (f4 & 7) << 2;
            int row = row0 + r;
            float4 v = make_float4(0.f, 0.f, 0.f, 0.f);
            if (row < M) v = *(const float4*)(X + (size_t)row * K + k0 + c);
            As[r][c] = v.x; As[r][c + 1] = v.y; As[r][c + 2] = v.z; As[r][c + 3] = v.w;
        }
#pragma unroll
        for (int i = 0; i < 8; ++i) {
            int f4 = tid + i * 256;
            int r = f4 >> 6, c = (f4 & 63) << 2;
            *(float4*)(&Ws[r][c]) = *(const float4*)(W + (size_t)(k0 + r) * HID + c);
        }
        __syncthreads();
#pragma unroll
        for (int kk = 0; kk < 32; ++kk) {
            float a[8];
#pragma unroll
            for (int i = 0; i < 8; ++i) a[i] = As[m0 + i][kk];
            const float4 w0 = *(const float4*)(&Ws[kk][n0]);
            const float4 w1 = *(const float4*)(&Ws[kk][n0 + 4]);
            const float b[8] = {w0.x, w0.y, w0.z, w0.w, w1.x, w1.y, w1.z, w1.w};
#pragma unroll
            for (int i = 0; i < 8; ++i)
#pragma unroll
                for (int j = 0; j < 8; ++j) acc[i][j] = fmaf(a[i], b[j], acc[i][j]);
        }
        __syncthreads();
    }
#pragma unroll
    for (int i = 0; i < 8; ++i) {
        int row = row0 + m0 + i;
        if (row < M) {
            float dv = dis[row];
            float4 o0 = make_float4(acc[i][0] * dv, acc[i][1] * dv, acc[i][2] * dv, acc[i][3] * dv);
            float4 o1 = make_float4(acc[i][4] * dv, acc[i][5] * dv, acc[i][6] * dv, acc[i][7] * dv);
            *(float4*)(Y + (size_t)row * HID + n0) = o0;
            *(float4*)(Y + (size_t)row * HID + n0 + 4) = o1;
            *(float4*)(Acc + (size_t)row * HID + n0) = o0;
            *(float4*)(Acc + (size_t)row * HID + n0 + 4) = o1;
        }
    }
}

// ---------------- aggregation: one wave per node, gather over CSR ----------------
// Acc[v] starts at y[v] (self loop). acc += y[src] for each in-edge, then
// h = relu(dis[v]*acc + bias) written back in place.
__global__ __launch_bounds__(256) void k_agg(const float* __restrict__ Y,
                                             float* __restrict__ Acc,
                                             const int* __restrict__ off,
                                             const int* __restrict__ csr,
                                             const float* __restrict__ dis,
                                             const float* __restrict__ bias, int n) {
    int lane = threadIdx.x & 63;
    int v = blockIdx.x * 4 + (threadIdx.x >> 6);
    if (v >= n) return;
    int beg = off[v], end = off[v + 1];
    const float4* Y4 = (const float4*)Y;
    float4* A4 = (float4*)Acc;
    float4 acc = A4[(size_t)v * 64 + lane];
    for (int e = beg; e < end; ++e) {
        int s = csr[e];
        float4 m = Y4[(size_t)s * 64 + lane];
        acc.x += m.x; acc.y += m.y; acc.z += m.z; acc.w += m.w;
    }
    float dv = dis[v];
    float4 bb = ((const float4*)bias)[lane];
    float4 h;
    h.x = fmaxf(fmaf(acc.x, dv, bb.x), 0.f);
    h.y = fmaxf(fmaf(acc.y, dv, bb.y), 0.f);
    h.z = fmaxf(fmaf(acc.z, dv, bb.z), 0.f);
    h.w = fmaxf(fmaf(acc.w, dv, bb.w), 0.f);
    A4[(size_t)v * 64 + lane] = h;
}

// ---------------- pooling ----------------
__global__ void k_gcnt(const int* __restrict__ batch, int* __restrict__ gcnt, int n) {
    for (int i = blockIdx.x * blockDim.x + threadIdx.x; i < n; i += gridDim.x * blockDim.x)
        atomicAdd(&gcnt[batch[i]], 1);
}

// 256 threads = 256 channels; each block walks 128 sorted nodes, one atomic per
// graph transition per channel.
__global__ __launch_bounds__(256) void k_pool(const float* __restrict__ H,
                                              const int* __restrict__ batch,
                                              float* __restrict__ out, int n) {
    int c = threadIdx.x;
    int n0 = blockIdx.x * 128;
    if (n0 >= n) return;
    int nEnd = min(n0 + 128, n);
    int g = batch[n0];
    float sum = 0.f;
    for (int i = n0; i < nEnd; ++i) {
        int gi = batch[i];
        if (gi != g) {
            atomicAdd(&out[(size_t)g * HID + c], sum);
            sum = 0.f;
            g = gi;
        }
        sum += H[(size_t)i * HID + c];
    }
    atomicAdd(&out[(size_t)g * HID + c], sum);
}

__global__ void k_div(float* __restrict__ out, const int* __restrict__ gcnt, int G) {
    int g = blockIdx.x;
    int c = threadIdx.x;
    float d = (float)max(gcnt[g], 1);
    out[(size_t)g * HID + c] /= d;
}

extern "C" void kernel_launch(void* const* d_in, const int* in_sizes, int n_in,
                              void* d_out, int out_size, void* d_ws, size_t ws_size,
                              hipStream_t stream) {
    const float* x = (const float*)d_in[0];
    const float* W1 = (const float*)d_in[1];
    const float* b1 = (const float*)d_in[2];
    const float* W2 = (const float*)d_in[3];
    const float* b2 = (const float*)d_in[4];
    const int* ei = (const int*)d_in[5];
    const int* batch = (const int*)d_in[6];
    float* out = (float*)d_out;

    const int N = in_sizes[6];        // 50000 nodes
    const int E = in_sizes[5] / 2;    // 800000 edges
    const int K1 = in_sizes[0] / N;   // 128
    const int G = out_size / HID;     // 500 graphs
    (void)K1; (void)n_in; (void)ws_size;

    char* w = (char*)d_ws;
    int* cnt = (int*)(w + 0);              // 50000 ints (reused as fill counters)
    float* dis = (float*)(w + 200704);     // 50000 f32
    int* off = (int*)(w + 401408);         // 50001 ints
    int* csr = (int*)(w + 602112);         // 800000 ints
    int* gcnt = (int*)(w + 3802112);       // 500 ints
    float* A = (float*)(w + 3804160);      // 50000*256 f32 (y buffer)
    float* B = (float*)(w + 55004160);     // 50000*256 f32 (acc / h buffer)

    hipMemsetAsync(cnt, 0, (size_t)N * sizeof(int), stream);
    hipMemsetAsync(gcnt, 0, (size_t)G * sizeof(int), stream);
    hipMemsetAsync(out, 0, (size_t)out_size * sizeof(float), stream);

    k_count<<<1024, 256, 0, stream>>>(ei + E, cnt, E);
    k_dis<<<(N + 255) / 256, 256, 0, stream>>>(cnt, dis, N);
    k_scan<<<1, 256, 0, stream>>>(cnt, off, N);
    hipMemsetAsync(cnt, 0, (size_t)N * sizeof(int), stream);
    k_fill<<<1024, 256, 0, stream>>>(ei, ei + E, off, cnt, csr, E);

    int gblk = (N + 63) / 64;
    // layer 1: y1 = (x @ W1)*dis -> A (and acc init in B)
    k_gemm<128><<<gblk, 256, 0, stream>>>(x, W1, dis, A, B, N);
    k_agg<<<(N + 3) / 4, 256, 0, stream>>>(A, B, off, csr, dis, b1, N);
    // layer 2: y2 = (h1 @ W2)*dis -> A (and acc init in B); each block reads only
    // its own rows of B before overwriting them, so in-place acc-init is safe.
    k_gemm<256><<<gblk, 256, 0, stream>>>(B, W2, dis, A, B, N);
    k_agg<<<(N + 3) / 4, 256, 0, stream>>>(A, B, off, csr, dis, b2, N);

    k_gcnt<<<(N + 255) / 256, 256, 0, stream>>>(batch, gcnt, N);
    k_pool<<<(N + 127) / 128, 256, 0, stream>>>(B, batch, out, N);
    k_div<<<G, HID, 0, stream>>>(out, gcnt, G);
}

// Round 2
// 402.726 us; speedup vs baseline: 1.6552x; 1.6552x over previous
//
#include <hip/hip_runtime.h>

#define HID 256
typedef unsigned short ushort_t;
typedef unsigned int uint_t;
typedef __attribute__((ext_vector_type(8))) short short8;
typedef __attribute__((ext_vector_type(4))) float f32x4;
typedef __attribute__((ext_vector_type(4))) unsigned short us4;
typedef __attribute__((ext_vector_type(8))) unsigned short us8;

__device__ __forceinline__ ushort_t f2b(float f) {
    uint_t u = __float_as_uint(f);
    u = u + 0x7fffu + ((u >> 16) & 1u);   // RNE
    return (ushort_t)(u >> 16);
}
__device__ __forceinline__ float b2f(ushort_t h) {
    return __uint_as_float(((uint_t)h) << 16);
}

// ---------------- degree count ----------------
__global__ void k_count(const int* __restrict__ dst, int* __restrict__ cnt, int E) {
    for (int i = blockIdx.x * blockDim.x + threadIdx.x; i < E; i += gridDim.x * blockDim.x)
        atomicAdd(&cnt[dst[i]], 1);
}

__global__ void k_dis(const int* __restrict__ cnt, float* __restrict__ dis, int n) {
    int i = blockIdx.x * blockDim.x + threadIdx.x;
    if (i < n) dis[i] = rsqrtf((float)(cnt[i] + 1));
}

// ---------------- exclusive scan (single block, 1024 threads) ----------------
__global__ __launch_bounds__(1024) void k_scan(const int* __restrict__ cnt, int* __restrict__ off, int n) {
    __shared__ int s[1024];
    int t = threadIdx.x;
    int C = (n + 1023) >> 10;
    int lo = t * C, hi = min(lo + C, n);
    int sum = 0;
    for (int i = lo; i < hi; ++i) sum += cnt[i];
    s[t] = sum;
    __syncthreads();
    for (int d = 1; d < 1024; d <<= 1) {
        int v = (t >= d) ? s[t - d] : 0;
        __syncthreads();
        s[t] += v;
        __syncthreads();
    }
    int run = s[t] - sum;
    for (int i = lo; i < hi; ++i) { off[i] = run; run += cnt[i]; }
    if (t == 1023) off[n] = s[1023];
}

// ---------------- CSR fill (by dst) ----------------
__global__ void k_fill(const int* __restrict__ src, const int* __restrict__ dst,
                       const int* __restrict__ off, int* __restrict__ fill,
                       int* __restrict__ csr, int E) {
    for (int i = blockIdx.x * blockDim.x + threadIdx.x; i < E; i += gridDim.x * blockDim.x) {
        int d = dst[i];
        int pos = off[d] + atomicAdd(&fill[d], 1);
        csr[pos] = src[i];
    }
}

// ---------------- cast x f32 -> bf16 ----------------
__global__ void k_cast(const float* __restrict__ x, ushort_t* __restrict__ xb, int total8) {
    int i = blockIdx.x * blockDim.x + threadIdx.x;
    if (i >= total8) return;
    const float4* p = (const float4*)(x + (size_t)i * 8);
    float4 v0 = p[0], v1 = p[1];
    us8 o;
    o[0] = f2b(v0.x); o[1] = f2b(v0.y); o[2] = f2b(v0.z); o[3] = f2b(v0.w);
    o[4] = f2b(v1.x); o[5] = f2b(v1.y); o[6] = f2b(v1.z); o[7] = f2b(v1.w);
    *(us8*)(xb + (size_t)i * 8) = o;
}

// ---------------- W -> transposed, bf16, K-panel-blocked, PRE-SWIZZLED ----------------
// Output: panels of 32768 B; panel p, element (c,k): logical LDS byte = c*128+k*2,
// swizzled 16B-slot: low3 ^= (c&7). Linear global_load_lds of a panel then yields the
// swizzled [col][k] layout in LDS directly.
__global__ void k_prep_wt(const float* __restrict__ W, ushort_t* __restrict__ Wt) {
    int kg = blockIdx.x;        // k row of W
    int c = threadIdx.x;        // 0..255 column
    float v = W[(size_t)kg * HID + c];
    int p = kg >> 6;
    int k = kg & 63;
    int byte_ = c * 128 + k * 2;
    int slot = byte_ >> 4;                      // c*8 + (k>>3)
    int sw = (slot & ~7) | ((slot ^ c) & 7);    // XOR low3 with c&7
    size_t dst_byte = (size_t)p * 32768 + ((size_t)sw << 4) + (byte_ & 15);
    Wt[dst_byte >> 1] = f2b(v);
}

// ---------------- MFMA GEMM: Y[row][c] = bf16( dis[row] * sum_k A[row][k]*W[k][c] ) ----
// A bf16 [M][K] row-major. Wt: pre-swizzled panels as above. Block: 128 rows x 256 cols,
// 8 waves (2 M x 4 N), wave tile 64x64. MFMA operands swapped (A-op = W^T, B-op = X)
// so D[i=c][j=row]; epilogue packs 4 consecutive channels per lane.
template <int K>
__global__ __launch_bounds__(512) void k_gemm_mfma(const ushort_t* __restrict__ A,
                                                   const ushort_t* __restrict__ Wt,
                                                   const float* __restrict__ dis,
                                                   ushort_t* __restrict__ Y, int M) {
    __shared__ char lds[49152];
    char* As = lds;            // 128 rows x 64 k bf16, swizzled: 16384 B
    char* Bs = lds + 16384;    // 256 cols x 64 k bf16, swizzled: 32768 B
    const int tid = threadIdx.x;
    const int lane = tid & 63;
    const int w = tid >> 6;
    const int wm = w & 1;      // m half (64 rows)
    const int wn = w >> 1;     // n quarter (64 cols)
    const int row0 = blockIdx.x * 128;

    f32x4 acc[4][4];
#pragma unroll
    for (int i = 0; i < 4; ++i)
#pragma unroll
        for (int j = 0; j < 4; ++j) acc[i][j] = (f32x4){0.f, 0.f, 0.f, 0.f};

    for (int k0 = 0; k0 < K; k0 += 64) {
        // stage A: 1024 slots of 16B; slot s holds logical (r=s>>3, kseg=(s&7)^(r&7))
#pragma unroll
        for (int q = 0; q < 2; ++q) {
            int s = q * 512 + tid;
            int r = s >> 3;
            int kseg = (s & 7) ^ (r & 7);
            int row = row0 + r;
            if (row >= M) row = 0;
            const ushort_t* g = A + (size_t)row * K + k0 + kseg * 8;
            __builtin_amdgcn_global_load_lds((const uint_t*)g,
                                             (uint_t*)(As + q * 8192 + w * 1024), 16, 0, 0);
        }
        // stage B: linear copy of pre-swizzled 32KB panel
        const ushort_t* gp = Wt + (size_t)(k0 >> 6) * (256 * 64);
#pragma unroll
        for (int q = 0; q < 4; ++q) {
            int s = q * 512 + tid;
            __builtin_amdgcn_global_load_lds((const uint_t*)(gp + (size_t)s * 8),
                                             (uint_t*)(Bs + q * 8192 + w * 1024), 16, 0, 0);
        }
        __syncthreads();
#pragma unroll
        for (int k32 = 0; k32 < 2; ++k32) {
            const int ksl = k32 * 4 + (lane >> 4);  // 16B-slot index along k
            short8 wf[4], xf[4];
#pragma unroll
            for (int nn = 0; nn < 4; ++nn) {
                int col = wn * 64 + nn * 16 + (lane & 15);
                int slot = col * 8 + (ksl ^ (col & 7));
                wf[nn] = *(const short8*)(Bs + slot * 16);
            }
#pragma unroll
            for (int m = 0; m < 4; ++m) {
                int row = wm * 64 + m * 16 + (lane & 15);
                int slot = row * 8 + (ksl ^ (row & 7));
                xf[m] = *(const short8*)(As + slot * 16);
            }
#pragma unroll
            for (int nn = 0; nn < 4; ++nn)
#pragma unroll
                for (int m = 0; m < 4; ++m)
                    acc[nn][m] = __builtin_amdgcn_mfma_f32_16x16x32_bf16(wf[nn], xf[m],
                                                                         acc[nn][m], 0, 0, 0);
        }
        __syncthreads();
    }
    // epilogue: D[i=c][j=row]; lane&15 = row-in-frag, (lane>>4)*4+reg = c-in-frag
    const int m_lo = lane & 15, c_hi = lane >> 4;
#pragma unroll
    for (int m = 0; m < 4; ++m) {
        int row = row0 + wm * 64 + m * 16 + m_lo;
        if (row < M) {
            float dv = dis[row];
#pragma unroll
            for (int nn = 0; nn < 4; ++nn) {
                int c0 = wn * 64 + nn * 16 + c_hi * 4;
                us4 o;
#pragma unroll
                for (int j = 0; j < 4; ++j) o[j] = f2b(acc[nn][m][j] * dv);
                *(us4*)(Y + (size_t)row * HID + c0) = o;
            }
        }
    }
}

// ---------------- aggregation: one wave per node, 2 edges per step (half-wave each) ---
// acc init = Y[v] (self loop term dis_v*xw_v). out = relu(dis_v*acc + bias), bf16.
__global__ __launch_bounds__(256) void k_agg(const ushort_t* __restrict__ Y,
                                             ushort_t* __restrict__ H,
                                             const int* __restrict__ off,
                                             const int* __restrict__ csr,
                                             const float* __restrict__ dis,
                                             const float* __restrict__ bias, int n) {
    int lane = threadIdx.x & 63;
    int v = blockIdx.x * 4 + (threadIdx.x >> 6);
    if (v >= n) return;
    int h = lane >> 5;         // which half-wave (edge parity)
    int l32 = lane & 31;       // 8 channels per lane
    float a0 = 0.f, a1 = 0.f, a2 = 0.f, a3 = 0.f, a4 = 0.f, a5 = 0.f, a6 = 0.f, a7 = 0.f;
    if (h == 0) {
        us8 sf = *(const us8*)(Y + (size_t)v * HID + l32 * 8);
        a0 = b2f(sf[0]); a1 = b2f(sf[1]); a2 = b2f(sf[2]); a3 = b2f(sf[3]);
        a4 = b2f(sf[4]); a5 = b2f(sf[5]); a6 = b2f(sf[6]); a7 = b2f(sf[7]);
    }
    int beg = off[v], end = off[v + 1];
    int e = beg + h;
    while (e + 2 < end) {
        int s0 = csr[e], s1 = csr[e + 2];
        us8 r0 = *(const us8*)(Y + (size_t)s0 * HID + l32 * 8);
        us8 r1 = *(const us8*)(Y + (size_t)s1 * HID + l32 * 8);
        a0 += b2f(r0[0]) + b2f(r1[0]); a1 += b2f(r0[1]) + b2f(r1[1]);
        a2 += b2f(r0[2]) + b2f(r1[2]); a3 += b2f(r0[3]) + b2f(r1[3]);
        a4 += b2f(r0[4]) + b2f(r1[4]); a5 += b2f(r0[5]) + b2f(r1[5]);
        a6 += b2f(r0[6]) + b2f(r1[6]); a7 += b2f(r0[7]) + b2f(r1[7]);
        e += 4;
    }
    if (e < end) {
        int s0 = csr[e];
        us8 r0 = *(const us8*)(Y + (size_t)s0 * HID + l32 * 8);
        a0 += b2f(r0[0]); a1 += b2f(r0[1]); a2 += b2f(r0[2]); a3 += b2f(r0[3]);
        a4 += b2f(r0[4]); a5 += b2f(r0[5]); a6 += b2f(r0[6]); a7 += b2f(r0[7]);
    }
    // merge the two halves
    a0 += __shfl_xor(a0, 32, 64); a1 += __shfl_xor(a1, 32, 64);
    a2 += __shfl_xor(a2, 32, 64); a3 += __shfl_xor(a3, 32, 64);
    a4 += __shfl_xor(a4, 32, 64); a5 += __shfl_xor(a5, 32, 64);
    a6 += __shfl_xor(a6, 32, 64); a7 += __shfl_xor(a7, 32, 64);
    if (h == 0) {
        float dv = dis[v];
        const float4* bp = (const float4*)(bias + l32 * 8);
        float4 b0 = bp[0], b1 = bp[1];
        us8 o;
        o[0] = f2b(fmaxf(fmaf(a0, dv, b0.x), 0.f));
        o[1] = f2b(fmaxf(fmaf(a1, dv, b0.y), 0.f));
        o[2] = f2b(fmaxf(fmaf(a2, dv, b0.z), 0.f));
        o[3] = f2b(fmaxf(fmaf(a3, dv, b0.w), 0.f));
        o[4] = f2b(fmaxf(fmaf(a4, dv, b1.x), 0.f));
        o[5] = f2b(fmaxf(fmaf(a5, dv, b1.y), 0.f));
        o[6] = f2b(fmaxf(fmaf(a6, dv, b1.z), 0.f));
        o[7] = f2b(fmaxf(fmaf(a7, dv, b1.w), 0.f));
        *(us8*)(H + (size_t)v * HID + l32 * 8) = o;
    }
}

// ---------------- pooling ----------------
__global__ void k_gcnt(const int* __restrict__ batch, int* __restrict__ gcnt, int n) {
    for (int i = blockIdx.x * blockDim.x + threadIdx.x; i < n; i += gridDim.x * blockDim.x)
        atomicAdd(&gcnt[batch[i]], 1);
}

__global__ __launch_bounds__(256) void k_pool(const ushort_t* __restrict__ H,
                                              const int* __restrict__ batch,
                                              float* __restrict__ out, int n) {
    int c = threadIdx.x;
    int n0 = blockIdx.x * 128;
    if (n0 >= n) return;
    int nEnd = min(n0 + 128, n);
    int g = batch[n0];
    float sum = 0.f;
    for (int i = n0; i < nEnd; ++i) {
        int gi = batch[i];
        if (gi != g) {
            atomicAdd(&out[(size_t)g * HID + c], sum);
            sum = 0.f;
            g = gi;
        }
        sum += b2f(H[(size_t)i * HID + c]);
    }
    atomicAdd(&out[(size_t)g * HID + c], sum);
}

__global__ void k_div(float* __restrict__ out, const int* __restrict__ gcnt, int G) {
    int g = blockIdx.x;
    int c = threadIdx.x;
    float d = (float)max(gcnt[g], 1);
    out[(size_t)g * HID + c] /= d;
}

extern "C" void kernel_launch(void* const* d_in, const int* in_sizes, int n_in,
                              void* d_out, int out_size, void* d_ws, size_t ws_size,
                              hipStream_t stream) {
    const float* x = (const float*)d_in[0];
    const float* W1 = (const float*)d_in[1];
    const float* b1 = (const float*)d_in[2];
    const float* W2 = (const float*)d_in[3];
    const float* b2 = (const float*)d_in[4];
    const int* ei = (const int*)d_in[5];
    const int* batch = (const int*)d_in[6];
    float* out = (float*)d_out;

    const int N = in_sizes[6];        // 50000
    const int E = in_sizes[5] / 2;    // 800000
    const int K1 = in_sizes[0] / N;   // 128
    const int G = out_size / HID;     // 500
    (void)n_in; (void)ws_size;

    char* w = (char*)d_ws;
    int* cnt = (int*)(w + 0);                       // 50000 i32
    float* dis = (float*)(w + 200704);              // 50000 f32
    int* off = (int*)(w + 401408);                  // 50001 i32
    int* csr = (int*)(w + 602112);                  // 800000 i32
    int* gcnt = (int*)(w + 3803136);                // 500 i32
    ushort_t* Wt1 = (ushort_t*)(w + 3805184);       // 128*256 bf16 (pre-swizzled panels)
    ushort_t* Wt2 = (ushort_t*)(w + 3870720);       // 256*256 bf16
    ushort_t* Xb = (ushort_t*)(w + 4001792);        // 50000*128 bf16
    ushort_t* Y  = (ushort_t*)(w + 16801792);       // 50000*256 bf16 (messages)
    ushort_t* H1 = (ushort_t*)(w + 42401792);       // 50000*256 bf16
    ushort_t* H2 = (ushort_t*)(w + 68001792);       // 50000*256 bf16

    hipMemsetAsync(cnt, 0, (size_t)N * sizeof(int), stream);
    hipMemsetAsync(gcnt, 0, (size_t)G * sizeof(int), stream);
    hipMemsetAsync(out, 0, (size_t)out_size * sizeof(float), stream);

    k_count<<<1024, 256, 0, stream>>>(ei + E, cnt, E);
    k_dis<<<(N + 255) / 256, 256, 0, stream>>>(cnt, dis, N);
    k_scan<<<1, 1024, 0, stream>>>(cnt, off, N);
    hipMemsetAsync(cnt, 0, (size_t)N * sizeof(int), stream);
    k_fill<<<1024, 256, 0, stream>>>(ei, ei + E, off, cnt, csr, E);

    k_cast<<<(N * K1 / 8 + 255) / 256, 256, 0, stream>>>(x, Xb, N * K1 / 8);
    k_prep_wt<<<K1, 256, 0, stream>>>(W1, Wt1);
    k_prep_wt<<<HID, 256, 0, stream>>>(W2, Wt2);

    int gblk = (N + 127) / 128;
    k_gemm_mfma<128><<<gblk, 512, 0, stream>>>(Xb, Wt1, dis, Y, N);
    k_agg<<<(N + 3) / 4, 256, 0, stream>>>(Y, H1, off, csr, dis, b1, N);
    k_gemm_mfma<256><<<gblk, 512, 0, stream>>>(H1, Wt2, dis, Y, N);
    k_agg<<<(N + 3) / 4, 256, 0, stream>>>(Y, H2, off, csr, dis, b2, N);

    k_gcnt<<<(N + 255) / 256, 256, 0, stream>>>(batch, gcnt, N);
    k_pool<<<(N + 127) / 128, 256, 0, stream>>>(H2, batch, out, N);
    k_div<<<G, HID, 0, stream>>>(out, gcnt, G);
}

// Round 3
// 338.327 us; speedup vs baseline: 1.9703x; 1.1903x over previous
//
#include <hip/hip_runtime.h>

#define HID 256
typedef unsigned short ushort_t;
typedef unsigned int uint_t;
typedef __attribute__((ext_vector_type(8))) short short8;
typedef __attribute__((ext_vector_type(4))) float f32x4;
typedef __attribute__((ext_vector_type(4))) unsigned short us4;
typedef __attribute__((ext_vector_type(8))) unsigned short us8;

__device__ __forceinline__ ushort_t f2b(float f) {
    uint_t u = __float_as_uint(f);
    u = u + 0x7fffu + ((u >> 16) & 1u);   // RNE
    return (ushort_t)(u >> 16);
}
__device__ __forceinline__ float b2f(ushort_t h) {
    return __uint_as_float(((uint_t)h) << 16);
}

// ---------------- degree count ----------------
__global__ void k_count(const int* __restrict__ dst, int* __restrict__ cnt, int E) {
    for (int i = blockIdx.x * blockDim.x + threadIdx.x; i < E; i += gridDim.x * blockDim.x)
        atomicAdd(&cnt[dst[i]], 1);
}

__global__ void k_dis(const int* __restrict__ cnt, float* __restrict__ dis, int n) {
    int i = blockIdx.x * blockDim.x + threadIdx.x;
    if (i < n) dis[i] = rsqrtf((float)(cnt[i] + 1));
}

// ---------------- hierarchical exclusive scan ----------------
// pass 1: block sums of 256-chunks
__global__ __launch_bounds__(256) void k_bsum(const int* __restrict__ cnt,
                                              int* __restrict__ bsum, int n) {
    __shared__ int s[256];
    int t = threadIdx.x;
    int i = blockIdx.x * 256 + t;
    s[t] = (i < n) ? cnt[i] : 0;
    __syncthreads();
#pragma unroll
    for (int d = 128; d > 0; d >>= 1) {
        if (t < d) s[t] += s[t + d];
        __syncthreads();
    }
    if (t == 0) bsum[blockIdx.x] = s[0];
}

// pass 2: exclusive scan of block sums (nb <= 256)
__global__ __launch_bounds__(256) void k_scan_bsum(const int* __restrict__ bsum,
                                                   int* __restrict__ boff, int nb) {
    __shared__ int s[256];
    int t = threadIdx.x;
    int v = (t < nb) ? bsum[t] : 0;
    s[t] = v;
    __syncthreads();
#pragma unroll
    for (int d = 1; d < 256; d <<= 1) {
        int u = (t >= d) ? s[t - d] : 0;
        __syncthreads();
        s[t] += u;
        __syncthreads();
    }
    if (t < nb) boff[t] = s[t] - v;
}

// pass 3: per-chunk exclusive scan + block offset; off[n] = E (static)
__global__ __launch_bounds__(256) void k_scan_fin(const int* __restrict__ cnt,
                                                  const int* __restrict__ boff,
                                                  int* __restrict__ off, int n, int E) {
    __shared__ int s[256];
    int t = threadIdx.x;
    int i = blockIdx.x * 256 + t;
    int v = (i < n) ? cnt[i] : 0;
    s[t] = v;
    __syncthreads();
#pragma unroll
    for (int d = 1; d < 256; d <<= 1) {
        int u = (t >= d) ? s[t - d] : 0;
        __syncthreads();
        s[t] += u;
        __syncthreads();
    }
    if (i < n) off[i] = boff[blockIdx.x] + s[t] - v;
    if (blockIdx.x == 0 && t == 0) off[n] = E;
}

// ---------------- CSR fill (by dst) ----------------
__global__ void k_fill(const int* __restrict__ src, const int* __restrict__ dst,
                       const int* __restrict__ off, int* __restrict__ fill,
                       int* __restrict__ csr, int E) {
    for (int i = blockIdx.x * blockDim.x + threadIdx.x; i < E; i += gridDim.x * blockDim.x) {
        int d = dst[i];
        int pos = off[d] + atomicAdd(&fill[d], 1);
        csr[pos] = src[i];
    }
}

// ---------------- cast x f32 -> bf16 ----------------
__global__ void k_cast(const float* __restrict__ x, ushort_t* __restrict__ xb, int total8) {
    int i = blockIdx.x * blockDim.x + threadIdx.x;
    if (i >= total8) return;
    const float4* p = (const float4*)(x + (size_t)i * 8);
    float4 v0 = p[0], v1 = p[1];
    us8 o;
    o[0] = f2b(v0.x); o[1] = f2b(v0.y); o[2] = f2b(v0.z); o[3] = f2b(v0.w);
    o[4] = f2b(v1.x); o[5] = f2b(v1.y); o[6] = f2b(v1.z); o[7] = f2b(v1.w);
    *(us8*)(xb + (size_t)i * 8) = o;
}

// ---------------- W -> transposed, bf16, K-panel-blocked, PRE-SWIZZLED ----------------
__global__ void k_prep_wt(const float* __restrict__ W, ushort_t* __restrict__ Wt) {
    int kg = blockIdx.x;        // k row of W
    int c = threadIdx.x;        // 0..255 column
    float v = W[(size_t)kg * HID + c];
    int p = kg >> 6;
    int k = kg & 63;
    int byte_ = c * 128 + k * 2;
    int slot = byte_ >> 4;                      // c*8 + (k>>3)
    int sw = (slot & ~7) | ((slot ^ c) & 7);    // XOR low3 with c&7
    size_t dst_byte = (size_t)p * 32768 + ((size_t)sw << 4) + (byte_ & 15);
    Wt[dst_byte >> 1] = f2b(v);
}

// ---------------- MFMA GEMM: Y[row][c] = bf16( dis[row] * sum_k A[row][k]*W[k][c] ) ----
template <int K>
__global__ __launch_bounds__(512) void k_gemm_mfma(const ushort_t* __restrict__ A,
                                                   const ushort_t* __restrict__ Wt,
                                                   const float* __restrict__ dis,
                                                   ushort_t* __restrict__ Y, int M) {
    __shared__ char lds[49152];
    char* As = lds;            // 128 rows x 64 k bf16, swizzled: 16384 B
    char* Bs = lds + 16384;    // 256 cols x 64 k bf16, swizzled: 32768 B
    const int tid = threadIdx.x;
    const int lane = tid & 63;
    const int w = tid >> 6;
    const int wm = w & 1;      // m half (64 rows)
    const int wn = w >> 1;     // n quarter (64 cols)
    const int row0 = blockIdx.x * 128;

    f32x4 acc[4][4];
#pragma unroll
    for (int i = 0; i < 4; ++i)
#pragma unroll
        for (int j = 0; j < 4; ++j) acc[i][j] = (f32x4){0.f, 0.f, 0.f, 0.f};

    for (int k0 = 0; k0 < K; k0 += 64) {
#pragma unroll
        for (int q = 0; q < 2; ++q) {
            int s = q * 512 + tid;
            int r = s >> 3;
            int kseg = (s & 7) ^ (r & 7);
            int row = row0 + r;
            if (row >= M) row = 0;
            const ushort_t* g = A + (size_t)row * K + k0 + kseg * 8;
            __builtin_amdgcn_global_load_lds((const uint_t*)g,
                                             (uint_t*)(As + q * 8192 + w * 1024), 16, 0, 0);
        }
        const ushort_t* gp = Wt + (size_t)(k0 >> 6) * (256 * 64);
#pragma unroll
        for (int q = 0; q < 4; ++q) {
            int s = q * 512 + tid;
            __builtin_amdgcn_global_load_lds((const uint_t*)(gp + (size_t)s * 8),
                                             (uint_t*)(Bs + q * 8192 + w * 1024), 16, 0, 0);
        }
        __syncthreads();
#pragma unroll
        for (int k32 = 0; k32 < 2; ++k32) {
            const int ksl = k32 * 4 + (lane >> 4);  // 16B-slot index along k
            short8 wf[4], xf[4];
#pragma unroll
            for (int nn = 0; nn < 4; ++nn) {
                int col = wn * 64 + nn * 16 + (lane & 15);
                int slot = col * 8 + (ksl ^ (col & 7));
                wf[nn] = *(const short8*)(Bs + slot * 16);
            }
#pragma unroll
            for (int m = 0; m < 4; ++m) {
                int row = wm * 64 + m * 16 + (lane & 15);
                int slot = row * 8 + (ksl ^ (row & 7));
                xf[m] = *(const short8*)(As + slot * 16);
            }
#pragma unroll
            for (int nn = 0; nn < 4; ++nn)
#pragma unroll
                for (int m = 0; m < 4; ++m)
                    acc[nn][m] = __builtin_amdgcn_mfma_f32_16x16x32_bf16(wf[nn], xf[m],
                                                                         acc[nn][m], 0, 0, 0);
        }
        __syncthreads();
    }
    const int m_lo = lane & 15, c_hi = lane >> 4;
#pragma unroll
    for (int m = 0; m < 4; ++m) {
        int row = row0 + wm * 64 + m * 16 + m_lo;
        if (row < M) {
            float dv = dis[row];
#pragma unroll
            for (int nn = 0; nn < 4; ++nn) {
                int c0 = wn * 64 + nn * 16 + c_hi * 4;
                us4 o;
#pragma unroll
                for (int j = 0; j < 4; ++j) o[j] = f2b(acc[nn][m][j] * dv);
                *(us4*)(Y + (size_t)row * HID + c0) = o;
            }
        }
    }
}

// ---------------- aggregation: one wave per node, 2 edges per step (half-wave each) ---
__global__ __launch_bounds__(256) void k_agg(const ushort_t* __restrict__ Y,
                                             ushort_t* __restrict__ H,
                                             const int* __restrict__ off,
                                             const int* __restrict__ csr,
                                             const float* __restrict__ dis,
                                             const float* __restrict__ bias, int n) {
    int lane = threadIdx.x & 63;
    int v = blockIdx.x * 4 + (threadIdx.x >> 6);
    if (v >= n) return;
    int h = lane >> 5;         // which half-wave (edge parity)
    int l32 = lane & 31;       // 8 channels per lane
    float a0 = 0.f, a1 = 0.f, a2 = 0.f, a3 = 0.f, a4 = 0.f, a5 = 0.f, a6 = 0.f, a7 = 0.f;
    if (h == 0) {
        us8 sf = *(const us8*)(Y + (size_t)v * HID + l32 * 8);
        a0 = b2f(sf[0]); a1 = b2f(sf[1]); a2 = b2f(sf[2]); a3 = b2f(sf[3]);
        a4 = b2f(sf[4]); a5 = b2f(sf[5]); a6 = b2f(sf[6]); a7 = b2f(sf[7]);
    }
    int beg = off[v], end = off[v + 1];
    int e = beg + h;
    while (e + 2 < end) {
        int s0 = csr[e], s1 = csr[e + 2];
        us8 r0 = *(const us8*)(Y + (size_t)s0 * HID + l32 * 8);
        us8 r1 = *(const us8*)(Y + (size_t)s1 * HID + l32 * 8);
        a0 += b2f(r0[0]) + b2f(r1[0]); a1 += b2f(r0[1]) + b2f(r1[1]);
        a2 += b2f(r0[2]) + b2f(r1[2]); a3 += b2f(r0[3]) + b2f(r1[3]);
        a4 += b2f(r0[4]) + b2f(r1[4]); a5 += b2f(r0[5]) + b2f(r1[5]);
        a6 += b2f(r0[6]) + b2f(r1[6]); a7 += b2f(r0[7]) + b2f(r1[7]);
        e += 4;
    }
    if (e < end) {
        int s0 = csr[e];
        us8 r0 = *(const us8*)(Y + (size_t)s0 * HID + l32 * 8);
        a0 += b2f(r0[0]); a1 += b2f(r0[1]); a2 += b2f(r0[2]); a3 += b2f(r0[3]);
        a4 += b2f(r0[4]); a5 += b2f(r0[5]); a6 += b2f(r0[6]); a7 += b2f(r0[7]);
    }
    a0 += __shfl_xor(a0, 32, 64); a1 += __shfl_xor(a1, 32, 64);
    a2 += __shfl_xor(a2, 32, 64); a3 += __shfl_xor(a3, 32, 64);
    a4 += __shfl_xor(a4, 32, 64); a5 += __shfl_xor(a5, 32, 64);
    a6 += __shfl_xor(a6, 32, 64); a7 += __shfl_xor(a7, 32, 64);
    if (h == 0) {
        float dv = dis[v];
        const float4* bp = (const float4*)(bias + l32 * 8);
        float4 b0 = bp[0], b1 = bp[1];
        us8 o;
        o[0] = f2b(fmaxf(fmaf(a0, dv, b0.x), 0.f));
        o[1] = f2b(fmaxf(fmaf(a1, dv, b0.y), 0.f));
        o[2] = f2b(fmaxf(fmaf(a2, dv, b0.z), 0.f));
        o[3] = f2b(fmaxf(fmaf(a3, dv, b0.w), 0.f));
        o[4] = f2b(fmaxf(fmaf(a4, dv, b1.x), 0.f));
        o[5] = f2b(fmaxf(fmaf(a5, dv, b1.y), 0.f));
        o[6] = f2b(fmaxf(fmaf(a6, dv, b1.z), 0.f));
        o[7] = f2b(fmaxf(fmaf(a7, dv, b1.w), 0.f));
        *(us8*)(H + (size_t)v * HID + l32 * 8) = o;
    }
}

// ---------------- pooling ----------------
__global__ void k_gcnt(const int* __restrict__ batch, int* __restrict__ gcnt, int n) {
    for (int i = blockIdx.x * blockDim.x + threadIdx.x; i < n; i += gridDim.x * blockDim.x)
        atomicAdd(&gcnt[batch[i]], 1);
}

__global__ __launch_bounds__(256) void k_pool(const ushort_t* __restrict__ H,
                                              const int* __restrict__ batch,
                                              float* __restrict__ out, int n) {
    int c = threadIdx.x;
    int n0 = blockIdx.x * 128;
    if (n0 >= n) return;
    int nEnd = min(n0 + 128, n);
    int g = batch[n0];
    float sum = 0.f;
    for (int i = n0; i < nEnd; ++i) {
        int gi = batch[i];
        if (gi != g) {
            atomicAdd(&out[(size_t)g * HID + c], sum);
            sum = 0.f;
            g = gi;
        }
        sum += b2f(H[(size_t)i * HID + c]);
    }
    atomicAdd(&out[(size_t)g * HID + c], sum);
}

__global__ void k_div(float* __restrict__ out, const int* __restrict__ gcnt, int G) {
    int g = blockIdx.x;
    int c = threadIdx.x;
    float d = (float)max(gcnt[g], 1);
    out[(size_t)g * HID + c] /= d;
}

extern "C" void kernel_launch(void* const* d_in, const int* in_sizes, int n_in,
                              void* d_out, int out_size, void* d_ws, size_t ws_size,
                              hipStream_t stream) {
    const float* x = (const float*)d_in[0];
    const float* W1 = (const float*)d_in[1];
    const float* b1 = (const float*)d_in[2];
    const float* W2 = (const float*)d_in[3];
    const float* b2 = (const float*)d_in[4];
    const int* ei = (const int*)d_in[5];
    const int* batch = (const int*)d_in[6];
    float* out = (float*)d_out;

    const int N = in_sizes[6];        // 50000
    const int E = in_sizes[5] / 2;    // 800000
    const int K1 = in_sizes[0] / N;   // 128
    const int G = out_size / HID;     // 500
    (void)n_in; (void)ws_size;

    char* w = (char*)d_ws;
    int* cnt = (int*)(w + 0);                       // 50000 i32
    float* dis = (float*)(w + 200704);              // 50000 f32
    int* off = (int*)(w + 401408);                  // 50001 i32
    int* csr = (int*)(w + 602112);                  // 800000 i32
    int* gcnt = (int*)(w + 3803136);                // 500 i32
    ushort_t* Wt1 = (ushort_t*)(w + 3805184);       // 128*256 bf16 (pre-swizzled panels)
    ushort_t* Wt2 = (ushort_t*)(w + 3870720);       // 256*256 bf16
    ushort_t* Xb = (ushort_t*)(w + 4001792);        // 50000*128 bf16
    ushort_t* Y  = (ushort_t*)(w + 16801792);       // 50000*256 bf16 (messages)
    ushort_t* H1 = (ushort_t*)(w + 42401792);       // 50000*256 bf16
    ushort_t* H2 = (ushort_t*)(w + 68001792);       // 50000*256 bf16
    int* bsum = (int*)(w + 93601792);               // 256 i32
    int* boff = (int*)(w + 93602816);               // 256 i32

    hipMemsetAsync(cnt, 0, (size_t)N * sizeof(int), stream);
    hipMemsetAsync(gcnt, 0, (size_t)G * sizeof(int), stream);
    hipMemsetAsync(out, 0, (size_t)out_size * sizeof(float), stream);

    const int nb = (N + 255) / 256;   // 196
    k_count<<<1024, 256, 0, stream>>>(ei + E, cnt, E);
    k_dis<<<(N + 255) / 256, 256, 0, stream>>>(cnt, dis, N);
    k_bsum<<<nb, 256, 0, stream>>>(cnt, bsum, N);
    k_scan_bsum<<<1, 256, 0, stream>>>(bsum, boff, nb);
    k_scan_fin<<<nb, 256, 0, stream>>>(cnt, boff, off, N, E);
    hipMemsetAsync(cnt, 0, (size_t)N * sizeof(int), stream);
    k_fill<<<1024, 256, 0, stream>>>(ei, ei + E, off, cnt, csr, E);

    k_cast<<<(N * K1 / 8 + 255) / 256, 256, 0, stream>>>(x, Xb, N * K1 / 8);
    k_prep_wt<<<K1, 256, 0, stream>>>(W1, Wt1);
    k_prep_wt<<<HID, 256, 0, stream>>>(W2, Wt2);

    int gblk = (N + 127) / 128;
    k_gemm_mfma<128><<<gblk, 512, 0, stream>>>(Xb, Wt1, dis, Y, N);
    k_agg<<<(N + 3) / 4, 256, 0, stream>>>(Y, H1, off, csr, dis, b1, N);
    k_gemm_mfma<256><<<gblk, 512, 0, stream>>>(H1, Wt2, dis, Y, N);
    k_agg<<<(N + 3) / 4, 256, 0, stream>>>(Y, H2, off, csr, dis, b2, N);

    k_gcnt<<<(N + 255) / 256, 256, 0, stream>>>(batch, gcnt, N);
    k_pool<<<(N + 127) / 128, 256, 0, stream>>>(H2, batch, out, N);
    k_div<<<G, HID, 0, stream>>>(out, gcnt, G);
}

// Round 4
// 310.660 us; speedup vs baseline: 2.1457x; 1.0891x over previous
//
#include <hip/hip_runtime.h>

#define HID 256
typedef unsigned short ushort_t;
typedef unsigned int uint_t;
typedef __attribute__((ext_vector_type(8))) short short8;
typedef __attribute__((ext_vector_type(4))) float f32x4;
typedef __attribute__((ext_vector_type(4))) unsigned short us4;
typedef __attribute__((ext_vector_type(8))) unsigned short us8;

__device__ __forceinline__ ushort_t f2b(float f) {
    uint_t u = __float_as_uint(f);
    u = u + 0x7fffu + ((u >> 16) & 1u);   // RNE
    return (ushort_t)(u >> 16);
}
__device__ __forceinline__ float b2f(ushort_t h) {
    return __uint_as_float(((uint_t)h) << 16);
}

// ---------------- degree count + graph count (fused) ----------------
__global__ void k_count2(const int* __restrict__ dst, int* __restrict__ cnt, int E,
                         const int* __restrict__ batch, int* __restrict__ gcnt, int n) {
    int stride = gridDim.x * blockDim.x;
    for (int i = blockIdx.x * blockDim.x + threadIdx.x; i < E; i += stride)
        atomicAdd(&cnt[dst[i]], 1);
    for (int i = blockIdx.x * blockDim.x + threadIdx.x; i < n; i += stride)
        atomicAdd(&gcnt[batch[i]], 1);
}

// ---------------- block sums + dis (fused) ----------------
__global__ __launch_bounds__(256) void k_bsum_dis(const int* __restrict__ cnt,
                                                  int* __restrict__ bsum,
                                                  float* __restrict__ dis, int n) {
    __shared__ int s[256];
    int t = threadIdx.x;
    int i = blockIdx.x * 256 + t;
    int c = (i < n) ? cnt[i] : 0;
    if (i < n) dis[i] = rsqrtf((float)(c + 1));
    s[t] = c;
    __syncthreads();
#pragma unroll
    for (int d = 128; d > 0; d >>= 1) {
        if (t < d) s[t] += s[t + d];
        __syncthreads();
    }
    if (t == 0) bsum[blockIdx.x] = s[0];
}

// exclusive scan of block sums (nb <= 256)
__global__ __launch_bounds__(256) void k_scan_bsum(const int* __restrict__ bsum,
                                                   int* __restrict__ boff, int nb) {
    __shared__ int s[256];
    int t = threadIdx.x;
    int v = (t < nb) ? bsum[t] : 0;
    s[t] = v;
    __syncthreads();
#pragma unroll
    for (int d = 1; d < 256; d <<= 1) {
        int u = (t >= d) ? s[t - d] : 0;
        __syncthreads();
        s[t] += u;
        __syncthreads();
    }
    if (t < nb) boff[t] = s[t] - v;
}

// per-chunk exclusive scan + block offset; writes off AND working copy woff
__global__ __launch_bounds__(256) void k_scan_fin(const int* __restrict__ cnt,
                                                  const int* __restrict__ boff,
                                                  int* __restrict__ off,
                                                  int* __restrict__ woff, int n, int E) {
    __shared__ int s[256];
    int t = threadIdx.x;
    int i = blockIdx.x * 256 + t;
    int v = (i < n) ? cnt[i] : 0;
    s[t] = v;
    __syncthreads();
#pragma unroll
    for (int d = 1; d < 256; d <<= 1) {
        int u = (t >= d) ? s[t - d] : 0;
        __syncthreads();
        s[t] += u;
        __syncthreads();
    }
    if (i < n) {
        int o = boff[blockIdx.x] + s[t] - v;
        off[i] = o;
        woff[i] = o;
    }
    if (blockIdx.x == 0 && t == 0) off[n] = E;
}

// ---------------- CSR fill (by dst); woff doubles as position counter ----------------
__global__ void k_fill(const int* __restrict__ src, const int* __restrict__ dst,
                       int* __restrict__ woff, int* __restrict__ csr, int E) {
    for (int i = blockIdx.x * blockDim.x + threadIdx.x; i < E; i += gridDim.x * blockDim.x) {
        int pos = atomicAdd(&woff[dst[i]], 1);
        csr[pos] = src[i];
    }
}

// ---------------- cast: Xd = bf16(dis[row] * x) ----------------
__global__ void k_cast(const float* __restrict__ x, const float* __restrict__ dis,
                       ushort_t* __restrict__ xd, int total8, int rshift) {
    int i = blockIdx.x * blockDim.x + threadIdx.x;
    if (i >= total8) return;
    float dv = dis[i >> rshift];
    const float4* p = (const float4*)(x + (size_t)i * 8);
    float4 v0 = p[0], v1 = p[1];
    us8 o;
    o[0] = f2b(v0.x * dv); o[1] = f2b(v0.y * dv); o[2] = f2b(v0.z * dv); o[3] = f2b(v0.w * dv);
    o[4] = f2b(v1.x * dv); o[5] = f2b(v1.y * dv); o[6] = f2b(v1.z * dv); o[7] = f2b(v1.w * dv);
    *(us8*)(xd + (size_t)i * 8) = o;
}

// ---------------- W -> transposed, bf16, K-panel-blocked, PRE-SWIZZLED ----------------
__global__ void k_prep_wt(const float* __restrict__ W, ushort_t* __restrict__ Wt) {
    int kg = blockIdx.x;        // k row of W
    int c = threadIdx.x;        // 0..255 column
    float v = W[(size_t)kg * HID + c];
    int p = kg >> 6;
    int k = kg & 63;
    int byte_ = c * 128 + k * 2;
    int slot = byte_ >> 4;
    int sw = (slot & ~7) | ((slot ^ c) & 7);
    size_t dst_byte = (size_t)p * 32768 + ((size_t)sw << 4) + (byte_ & 15);
    Wt[dst_byte >> 1] = f2b(v);
}

// ---------------- aggregation: Z[v] = bf16( dis_v * (Y[v] + sum_{s in csr} Y[s]) ) ----
// LPR lanes per row (16 -> 128ch, 32 -> 256ch); each lane 8 channels (16B).
template <int LPR>
__global__ __launch_bounds__(256) void k_agg(const ushort_t* __restrict__ Y,
                                             ushort_t* __restrict__ Z,
                                             const int* __restrict__ off,
                                             const int* __restrict__ csr,
                                             const float* __restrict__ dis, int n) {
    const int CH = LPR * 8;
    const int P = 64 / LPR;            // edge parities per wave
    int lane = threadIdx.x & 63;
    int v = blockIdx.x * 4 + (threadIdx.x >> 6);
    if (v >= n) return;
    int par = lane / LPR;
    int sub = lane % LPR;
    float a0 = 0.f, a1 = 0.f, a2 = 0.f, a3 = 0.f, a4 = 0.f, a5 = 0.f, a6 = 0.f, a7 = 0.f;
    if (par == 0) {
        us8 sf = *(const us8*)(Y + (size_t)v * CH + sub * 8);
        a0 = b2f(sf[0]); a1 = b2f(sf[1]); a2 = b2f(sf[2]); a3 = b2f(sf[3]);
        a4 = b2f(sf[4]); a5 = b2f(sf[5]); a6 = b2f(sf[6]); a7 = b2f(sf[7]);
    }
    int e = off[v] + par, end = off[v + 1];
    while (e + 3 * P < end) {
        int s0 = csr[e], s1 = csr[e + P], s2 = csr[e + 2 * P], s3 = csr[e + 3 * P];
        us8 r0 = *(const us8*)(Y + (size_t)s0 * CH + sub * 8);
        us8 r1 = *(const us8*)(Y + (size_t)s1 * CH + sub * 8);
        us8 r2 = *(const us8*)(Y + (size_t)s2 * CH + sub * 8);
        us8 r3 = *(const us8*)(Y + (size_t)s3 * CH + sub * 8);
        a0 += (b2f(r0[0]) + b2f(r1[0])) + (b2f(r2[0]) + b2f(r3[0]));
        a1 += (b2f(r0[1]) + b2f(r1[1])) + (b2f(r2[1]) + b2f(r3[1]));
        a2 += (b2f(r0[2]) + b2f(r1[2])) + (b2f(r2[2]) + b2f(r3[2]));
        a3 += (b2f(r0[3]) + b2f(r1[3])) + (b2f(r2[3]) + b2f(r3[3]));
        a4 += (b2f(r0[4]) + b2f(r1[4])) + (b2f(r2[4]) + b2f(r3[4]));
        a5 += (b2f(r0[5]) + b2f(r1[5])) + (b2f(r2[5]) + b2f(r3[5]));
        a6 += (b2f(r0[6]) + b2f(r1[6])) + (b2f(r2[6]) + b2f(r3[6]));
        a7 += (b2f(r0[7]) + b2f(r1[7])) + (b2f(r2[7]) + b2f(r3[7]));
        e += 4 * P;
    }
    while (e < end) {
        int s0 = csr[e];
        us8 r0 = *(const us8*)(Y + (size_t)s0 * CH + sub * 8);
        a0 += b2f(r0[0]); a1 += b2f(r0[1]); a2 += b2f(r0[2]); a3 += b2f(r0[3]);
        a4 += b2f(r0[4]); a5 += b2f(r0[5]); a6 += b2f(r0[6]); a7 += b2f(r0[7]);
        e += P;
    }
#pragma unroll
    for (int d = LPR; d < 64; d <<= 1) {
        a0 += __shfl_xor(a0, d, 64); a1 += __shfl_xor(a1, d, 64);
        a2 += __shfl_xor(a2, d, 64); a3 += __shfl_xor(a3, d, 64);
        a4 += __shfl_xor(a4, d, 64); a5 += __shfl_xor(a5, d, 64);
        a6 += __shfl_xor(a6, d, 64); a7 += __shfl_xor(a7, d, 64);
    }
    if (par == 0) {
        float dv = dis[v];
        us8 o;
        o[0] = f2b(a0 * dv); o[1] = f2b(a1 * dv); o[2] = f2b(a2 * dv); o[3] = f2b(a3 * dv);
        o[4] = f2b(a4 * dv); o[5] = f2b(a5 * dv); o[6] = f2b(a6 * dv); o[7] = f2b(a7 * dv);
        *(us8*)(Z + (size_t)v * CH + sub * 8) = o;
    }
}

// ---------------- MFMA GEMM: Yout[row][c] = bf16( post( A[row]·W[:,c] + bias[c] ) ) ----
// post = relu, then (SCALE ? *dis[row] : identity)
template <int K, bool SCALE>
__global__ __launch_bounds__(512) void k_gemm_mfma(const ushort_t* __restrict__ A,
                                                   const ushort_t* __restrict__ Wt,
                                                   const float* __restrict__ dis,
                                                   const float* __restrict__ bias,
                                                   ushort_t* __restrict__ Yout, int M) {
    __shared__ char lds[49152];
    char* As = lds;            // 128 rows x 64 k bf16, swizzled: 16384 B
    char* Bs = lds + 16384;    // 256 cols x 64 k bf16, swizzled: 32768 B
    const int tid = threadIdx.x;
    const int lane = tid & 63;
    const int w = tid >> 6;
    const int wm = w & 1;
    const int wn = w >> 1;
    const int row0 = blockIdx.x * 128;

    f32x4 acc[4][4];
#pragma unroll
    for (int i = 0; i < 4; ++i)
#pragma unroll
        for (int j = 0; j < 4; ++j) acc[i][j] = (f32x4){0.f, 0.f, 0.f, 0.f};

    for (int k0 = 0; k0 < K; k0 += 64) {
#pragma unroll
        for (int q = 0; q < 2; ++q) {
            int s = q * 512 + tid;
            int r = s >> 3;
            int kseg = (s & 7) ^ (r & 7);
            int row = row0 + r;
            if (row >= M) row = 0;
            const ushort_t* g = A + (size_t)row * K + k0 + kseg * 8;
            __builtin_amdgcn_global_load_lds((const uint_t*)g,
                                             (uint_t*)(As + q * 8192 + w * 1024), 16, 0, 0);
        }
        const ushort_t* gp = Wt + (size_t)(k0 >> 6) * (256 * 64);
#pragma unroll
        for (int q = 0; q < 4; ++q) {
            int s = q * 512 + tid;
            __builtin_amdgcn_global_load_lds((const uint_t*)(gp + (size_t)s * 8),
                                             (uint_t*)(Bs + q * 8192 + w * 1024), 16, 0, 0);
        }
        __syncthreads();
#pragma unroll
        for (int k32 = 0; k32 < 2; ++k32) {
            const int ksl = k32 * 4 + (lane >> 4);
            short8 wf[4], xf[4];
#pragma unroll
            for (int nn = 0; nn < 4; ++nn) {
                int col = wn * 64 + nn * 16 + (lane & 15);
                int slot = col * 8 + (ksl ^ (col & 7));
                wf[nn] = *(const short8*)(Bs + slot * 16);
            }
#pragma unroll
            for (int m = 0; m < 4; ++m) {
                int row = wm * 64 + m * 16 + (lane & 15);
                int slot = row * 8 + (ksl ^ (row & 7));
                xf[m] = *(const short8*)(As + slot * 16);
            }
#pragma unroll
            for (int nn = 0; nn < 4; ++nn)
#pragma unroll
                for (int m = 0; m < 4; ++m)
                    acc[nn][m] = __builtin_amdgcn_mfma_f32_16x16x32_bf16(wf[nn], xf[m],
                                                                         acc[nn][m], 0, 0, 0);
        }
        __syncthreads();
    }
    const int m_lo = lane & 15, c_hi = lane >> 4;
#pragma unroll
    for (int m = 0; m < 4; ++m) {
        int row = row0 + wm * 64 + m * 16 + m_lo;
        if (row < M) {
            float dv = SCALE ? dis[row] : 1.f;
#pragma unroll
            for (int nn = 0; nn < 4; ++nn) {
                int c0 = wn * 64 + nn * 16 + c_hi * 4;
                float4 bb = *(const float4*)(bias + c0);
                us4 o;
                o[0] = f2b(fmaxf(acc[nn][m][0] + bb.x, 0.f) * dv);
                o[1] = f2b(fmaxf(acc[nn][m][1] + bb.y, 0.f) * dv);
                o[2] = f2b(fmaxf(acc[nn][m][2] + bb.z, 0.f) * dv);
                o[3] = f2b(fmaxf(acc[nn][m][3] + bb.w, 0.f) * dv);
                *(us4*)(Yout + (size_t)row * HID + c0) = o;
            }
        }
    }
}

// ---------------- pooling ----------------
__global__ __launch_bounds__(256) void k_pool(const ushort_t* __restrict__ H,
                                              const int* __restrict__ batch,
                                              float* __restrict__ out, int n) {
    int c = threadIdx.x;
    int n0 = blockIdx.x * 128;
    if (n0 >= n) return;
    int nEnd = min(n0 + 128, n);
    int g = batch[n0];
    float sum = 0.f;
    for (int i = n0; i < nEnd; ++i) {
        int gi = batch[i];
        if (gi != g) {
            atomicAdd(&out[(size_t)g * HID + c], sum);
            sum = 0.f;
            g = gi;
        }
        sum += b2f(H[(size_t)i * HID + c]);
    }
    atomicAdd(&out[(size_t)g * HID + c], sum);
}

__global__ void k_div(float* __restrict__ out, const int* __restrict__ gcnt, int G) {
    int g = blockIdx.x;
    int c = threadIdx.x;
    float d = (float)max(gcnt[g], 1);
    out[(size_t)g * HID + c] /= d;
}

extern "C" void kernel_launch(void* const* d_in, const int* in_sizes, int n_in,
                              void* d_out, int out_size, void* d_ws, size_t ws_size,
                              hipStream_t stream) {
    const float* x = (const float*)d_in[0];
    const float* W1 = (const float*)d_in[1];
    const float* b1 = (const float*)d_in[2];
    const float* W2 = (const float*)d_in[3];
    const float* b2 = (const float*)d_in[4];
    const int* ei = (const int*)d_in[5];
    const int* batch = (const int*)d_in[6];
    float* out = (float*)d_out;

    const int N = in_sizes[6];        // 50000
    const int E = in_sizes[5] / 2;    // 800000
    const int K1 = in_sizes[0] / N;   // 128
    const int G = out_size / HID;     // 500
    (void)n_in; (void)ws_size;

    char* w = (char*)d_ws;
    int* cnt = (int*)(w + 0);                       // 50000 i32
    float* dis = (float*)(w + 200704);              // 50000 f32
    int* off = (int*)(w + 401408);                  // 50001 i32
    int* woff = (int*)(w + 602112);                 // 50000 i32 (working copy)
    int* csr = (int*)(w + 802816);                  // 800000 i32
    int* gcnt = (int*)(w + 4003840);                // 500 i32
    int* bsum = (int*)(w + 4005888);                // 256 i32
    int* boff = (int*)(w + 4006912);                // 256 i32
    ushort_t* Wt1 = (ushort_t*)(w + 4007936);       // 128*256 bf16 pre-swizzled
    ushort_t* Wt2 = (ushort_t*)(w + 4073472);       // 256*256 bf16
    ushort_t* Xd = (ushort_t*)(w + 4204544);        // 50000*128 bf16 (dis*x)
    ushort_t* Z1 = (ushort_t*)(w + 17004544);       // 50000*128 bf16
    ushort_t* H1d = (ushort_t*)(w + 29804544);      // 50000*256 bf16 (dis*relu)
    ushort_t* Z2 = (ushort_t*)(w + 55404544);       // 50000*256 bf16
    ushort_t* H2 = (ushort_t*)(w + 4204544);        // 50000*256 bf16 (aliases Xd+Z1, both dead)

    hipMemsetAsync(cnt, 0, (size_t)N * sizeof(int), stream);
    hipMemsetAsync(gcnt, 0, (size_t)G * sizeof(int), stream);
    hipMemsetAsync(out, 0, (size_t)out_size * sizeof(float), stream);

    const int nb = (N + 255) / 256;   // 196
    k_count2<<<1024, 256, 0, stream>>>(ei + E, cnt, E, batch, gcnt, N);
    k_bsum_dis<<<nb, 256, 0, stream>>>(cnt, bsum, dis, N);
    k_scan_bsum<<<1, 256, 0, stream>>>(bsum, boff, nb);
    k_scan_fin<<<nb, 256, 0, stream>>>(cnt, boff, off, woff, N, E);
    k_fill<<<1024, 256, 0, stream>>>(ei, ei + E, woff, csr, E);

    int rshift = 31 - __builtin_clz((unsigned)(K1 / 8));   // log2(K1/8) = 4
    k_cast<<<(N * K1 / 8 + 255) / 256, 256, 0, stream>>>(x, dis, Xd, N * K1 / 8, rshift);
    k_prep_wt<<<K1, 256, 0, stream>>>(W1, Wt1);
    k_prep_wt<<<HID, 256, 0, stream>>>(W2, Wt2);

    int gblk = (N + 127) / 128;
    // layer 1: aggregate first (128 ch), then GEMM with fused bias+relu+dis
    k_agg<16><<<(N + 3) / 4, 256, 0, stream>>>(Xd, Z1, off, csr, dis, N);
    k_gemm_mfma<128, true><<<gblk, 512, 0, stream>>>(Z1, Wt1, dis, b1, H1d, N);
    // layer 2: aggregate (256 ch), then GEMM with fused bias+relu
    k_agg<32><<<(N + 3) / 4, 256, 0, stream>>>(H1d, Z2, off, csr, dis, N);
    k_gemm_mfma<256, false><<<gblk, 512, 0, stream>>>(Z2, Wt2, dis, b2, H2, N);

    k_pool<<<(N + 127) / 128, 256, 0, stream>>>(H2, batch, out, N);
    k_div<<<G, HID, 0, stream>>>(out, gcnt, G);
}

// Round 5
// 286.661 us; speedup vs baseline: 2.3254x; 1.0837x over previous
//
#include <hip/hip_runtime.h>

#define HID 256
typedef unsigned short ushort_t;
typedef unsigned int uint_t;
typedef __attribute__((ext_vector_type(8))) short short8;
typedef __attribute__((ext_vector_type(4))) float f32x4;
typedef __attribute__((ext_vector_type(4))) unsigned short us4;
typedef __attribute__((ext_vector_type(8))) unsigned short us8;

__device__ __forceinline__ ushort_t f2b(float f) {
    uint_t u = __float_as_uint(f);
    u = u + 0x7fffu + ((u >> 16) & 1u);   // RNE
    return (ushort_t)(u >> 16);
}
__device__ __forceinline__ float b2f(ushort_t h) {
    return __uint_as_float(((uint_t)h) << 16);
}

// ---------------- degree count (edge-only, 1 edge/thread) ----------------
__global__ __launch_bounds__(256) void k_count(const int* __restrict__ dst,
                                               int* __restrict__ cnt, int E) {
    int i = blockIdx.x * 256 + threadIdx.x;
    if (i < E) atomicAdd(&cnt[dst[i]], 1);
}

// ---------------- graph counts via binary search (batch sorted, no atomics) ----------
__global__ __launch_bounds__(256) void k_gcnt_search(const int* __restrict__ batch,
                                                     int* __restrict__ gcnt, int n, int G) {
    int g = blockIdx.x * 256 + threadIdx.x;
    if (g >= G) return;
    // lower_bound(g)
    int lo = 0, hi = n;
    while (lo < hi) { int mid = (lo + hi) >> 1; if (batch[mid] < g) lo = mid + 1; else hi = mid; }
    int lb = lo;
    // lower_bound(g+1)
    hi = n;
    while (lo < hi) { int mid = (lo + hi) >> 1; if (batch[mid] < g + 1) lo = mid + 1; else hi = mid; }
    gcnt[g] = lo - lb;
}

// ---------------- block sums + dis (fused) ----------------
__global__ __launch_bounds__(256) void k_bsum_dis(const int* __restrict__ cnt,
                                                  int* __restrict__ bsum,
                                                  float* __restrict__ dis, int n) {
    __shared__ int s[256];
    int t = threadIdx.x;
    int i = blockIdx.x * 256 + t;
    int c = (i < n) ? cnt[i] : 0;
    if (i < n) dis[i] = rsqrtf((float)(c + 1));
    s[t] = c;
    __syncthreads();
#pragma unroll
    for (int d = 128; d > 0; d >>= 1) {
        if (t < d) s[t] += s[t + d];
        __syncthreads();
    }
    if (t == 0) bsum[blockIdx.x] = s[0];
}

// exclusive scan of block sums (nb <= 256)
__global__ __launch_bounds__(256) void k_scan_bsum(const int* __restrict__ bsum,
                                                   int* __restrict__ boff, int nb) {
    __shared__ int s[256];
    int t = threadIdx.x;
    int v = (t < nb) ? bsum[t] : 0;
    s[t] = v;
    __syncthreads();
#pragma unroll
    for (int d = 1; d < 256; d <<= 1) {
        int u = (t >= d) ? s[t - d] : 0;
        __syncthreads();
        s[t] += u;
        __syncthreads();
    }
    if (t < nb) boff[t] = s[t] - v;
}

// per-chunk exclusive scan + block offset; writes off AND working copy woff
__global__ __launch_bounds__(256) void k_scan_fin(const int* __restrict__ cnt,
                                                  const int* __restrict__ boff,
                                                  int* __restrict__ off,
                                                  int* __restrict__ woff, int n, int E) {
    __shared__ int s[256];
    int t = threadIdx.x;
    int i = blockIdx.x * 256 + t;
    int v = (i < n) ? cnt[i] : 0;
    s[t] = v;
    __syncthreads();
#pragma unroll
    for (int d = 1; d < 256; d <<= 1) {
        int u = (t >= d) ? s[t - d] : 0;
        __syncthreads();
        s[t] += u;
        __syncthreads();
    }
    if (i < n) {
        int o = boff[blockIdx.x] + s[t] - v;
        off[i] = o;
        woff[i] = o;
    }
    if (blockIdx.x == 0 && t == 0) off[n] = E;
}

// ---------------- CSR fill (by dst); woff doubles as position counter ----------------
__global__ __launch_bounds__(256) void k_fill(const int* __restrict__ src,
                                              const int* __restrict__ dst,
                                              int* __restrict__ woff,
                                              int* __restrict__ csr, int E) {
    int i = blockIdx.x * 256 + threadIdx.x;
    if (i < E) {
        int pos = atomicAdd(&woff[dst[i]], 1);
        csr[pos] = src[i];
    }
}

// ---------------- cast: Xd = bf16(dis[row] * x) ----------------
__global__ void k_cast(const float* __restrict__ x, const float* __restrict__ dis,
                       ushort_t* __restrict__ xd, int total8, int rshift) {
    int i = blockIdx.x * blockDim.x + threadIdx.x;
    if (i >= total8) return;
    float dv = dis[i >> rshift];
    const float4* p = (const float4*)(x + (size_t)i * 8);
    float4 v0 = p[0], v1 = p[1];
    us8 o;
    o[0] = f2b(v0.x * dv); o[1] = f2b(v0.y * dv); o[2] = f2b(v0.z * dv); o[3] = f2b(v0.w * dv);
    o[4] = f2b(v1.x * dv); o[5] = f2b(v1.y * dv); o[6] = f2b(v1.z * dv); o[7] = f2b(v1.w * dv);
    *(us8*)(xd + (size_t)i * 8) = o;
}

// ---------------- W -> transposed, bf16, K-panel-blocked, PRE-SWIZZLED ----------------
__global__ void k_prep_wt(const float* __restrict__ W, ushort_t* __restrict__ Wt) {
    int kg = blockIdx.x;        // k row of W
    int c = threadIdx.x;        // 0..255 column
    float v = W[(size_t)kg * HID + c];
    int p = kg >> 6;
    int k = kg & 63;
    int byte_ = c * 128 + k * 2;
    int slot = byte_ >> 4;
    int sw = (slot & ~7) | ((slot ^ c) & 7);
    size_t dst_byte = (size_t)p * 32768 + ((size_t)sw << 4) + (byte_ & 15);
    Wt[dst_byte >> 1] = f2b(v);
}

// ---------------- aggregation: Z[v] = bf16( dis_v * (Y[v] + sum_{s in csr} Y[s]) ) ----
template <int LPR>
__global__ __launch_bounds__(256) void k_agg(const ushort_t* __restrict__ Y,
                                             ushort_t* __restrict__ Z,
                                             const int* __restrict__ off,
                                             const int* __restrict__ csr,
                                             const float* __restrict__ dis, int n) {
    const int CH = LPR * 8;
    const int P = 64 / LPR;            // edge parities per wave
    int lane = threadIdx.x & 63;
    int v = blockIdx.x * 4 + (threadIdx.x >> 6);
    if (v >= n) return;
    int par = lane / LPR;
    int sub = lane % LPR;
    float a0 = 0.f, a1 = 0.f, a2 = 0.f, a3 = 0.f, a4 = 0.f, a5 = 0.f, a6 = 0.f, a7 = 0.f;
    if (par == 0) {
        us8 sf = *(const us8*)(Y + (size_t)v * CH + sub * 8);
        a0 = b2f(sf[0]); a1 = b2f(sf[1]); a2 = b2f(sf[2]); a3 = b2f(sf[3]);
        a4 = b2f(sf[4]); a5 = b2f(sf[5]); a6 = b2f(sf[6]); a7 = b2f(sf[7]);
    }
    int e = off[v] + par, end = off[v + 1];
    while (e + 3 * P < end) {
        int s0 = csr[e], s1 = csr[e + P], s2 = csr[e + 2 * P], s3 = csr[e + 3 * P];
        us8 r0 = *(const us8*)(Y + (size_t)s0 * CH + sub * 8);
        us8 r1 = *(const us8*)(Y + (size_t)s1 * CH + sub * 8);
        us8 r2 = *(const us8*)(Y + (size_t)s2 * CH + sub * 8);
        us8 r3 = *(const us8*)(Y + (size_t)s3 * CH + sub * 8);
        a0 += (b2f(r0[0]) + b2f(r1[0])) + (b2f(r2[0]) + b2f(r3[0]));
        a1 += (b2f(r0[1]) + b2f(r1[1])) + (b2f(r2[1]) + b2f(r3[1]));
        a2 += (b2f(r0[2]) + b2f(r1[2])) + (b2f(r2[2]) + b2f(r3[2]));
        a3 += (b2f(r0[3]) + b2f(r1[3])) + (b2f(r2[3]) + b2f(r3[3]));
        a4 += (b2f(r0[4]) + b2f(r1[4])) + (b2f(r2[4]) + b2f(r3[4]));
        a5 += (b2f(r0[5]) + b2f(r1[5])) + (b2f(r2[5]) + b2f(r3[5]));
        a6 += (b2f(r0[6]) + b2f(r1[6])) + (b2f(r2[6]) + b2f(r3[6]));
        a7 += (b2f(r0[7]) + b2f(r1[7])) + (b2f(r2[7]) + b2f(r3[7]));
        e += 4 * P;
    }
    while (e < end) {
        int s0 = csr[e];
        us8 r0 = *(const us8*)(Y + (size_t)s0 * CH + sub * 8);
        a0 += b2f(r0[0]); a1 += b2f(r0[1]); a2 += b2f(r0[2]); a3 += b2f(r0[3]);
        a4 += b2f(r0[4]); a5 += b2f(r0[5]); a6 += b2f(r0[6]); a7 += b2f(r0[7]);
        e += P;
    }
#pragma unroll
    for (int d = LPR; d < 64; d <<= 1) {
        a0 += __shfl_xor(a0, d, 64); a1 += __shfl_xor(a1, d, 64);
        a2 += __shfl_xor(a2, d, 64); a3 += __shfl_xor(a3, d, 64);
        a4 += __shfl_xor(a4, d, 64); a5 += __shfl_xor(a5, d, 64);
        a6 += __shfl_xor(a6, d, 64); a7 += __shfl_xor(a7, d, 64);
    }
    if (par == 0) {
        float dv = dis[v];
        us8 o;
        o[0] = f2b(a0 * dv); o[1] = f2b(a1 * dv); o[2] = f2b(a2 * dv); o[3] = f2b(a3 * dv);
        o[4] = f2b(a4 * dv); o[5] = f2b(a5 * dv); o[6] = f2b(a6 * dv); o[7] = f2b(a7 * dv);
        *(us8*)(Z + (size_t)v * CH + sub * 8) = o;
    }
}

// ---------------- MFMA GEMM: Yout[row][c] = bf16( post( A[row]·W[:,c] + bias[c] ) ) ----
template <int K, bool SCALE>
__global__ __launch_bounds__(512) void k_gemm_mfma(const ushort_t* __restrict__ A,
                                                   const ushort_t* __restrict__ Wt,
                                                   const float* __restrict__ dis,
                                                   const float* __restrict__ bias,
                                                   ushort_t* __restrict__ Yout, int M) {
    __shared__ char lds[49152];
    char* As = lds;            // 128 rows x 64 k bf16, swizzled: 16384 B
    char* Bs = lds + 16384;    // 256 cols x 64 k bf16, swizzled: 32768 B
    const int tid = threadIdx.x;
    const int lane = tid & 63;
    const int w = tid >> 6;
    const int wm = w & 1;
    const int wn = w >> 1;
    const int row0 = blockIdx.x * 128;

    f32x4 acc[4][4];
#pragma unroll
    for (int i = 0; i < 4; ++i)
#pragma unroll
        for (int j = 0; j < 4; ++j) acc[i][j] = (f32x4){0.f, 0.f, 0.f, 0.f};

    for (int k0 = 0; k0 < K; k0 += 64) {
#pragma unroll
        for (int q = 0; q < 2; ++q) {
            int s = q * 512 + tid;
            int r = s >> 3;
            int kseg = (s & 7) ^ (r & 7);
            int row = row0 + r;
            if (row >= M) row = 0;
            const ushort_t* g = A + (size_t)row * K + k0 + kseg * 8;
            __builtin_amdgcn_global_load_lds((const uint_t*)g,
                                             (uint_t*)(As + q * 8192 + w * 1024), 16, 0, 0);
        }
        const ushort_t* gp = Wt + (size_t)(k0 >> 6) * (256 * 64);
#pragma unroll
        for (int q = 0; q < 4; ++q) {
            int s = q * 512 + tid;
            __builtin_amdgcn_global_load_lds((const uint_t*)(gp + (size_t)s * 8),
                                             (uint_t*)(Bs + q * 8192 + w * 1024), 16, 0, 0);
        }
        __syncthreads();
#pragma unroll
        for (int k32 = 0; k32 < 2; ++k32) {
            const int ksl = k32 * 4 + (lane >> 4);
            short8 wf[4], xf[4];
#pragma unroll
            for (int nn = 0; nn < 4; ++nn) {
                int col = wn * 64 + nn * 16 + (lane & 15);
                int slot = col * 8 + (ksl ^ (col & 7));
                wf[nn] = *(const short8*)(Bs + slot * 16);
            }
#pragma unroll
            for (int m = 0; m < 4; ++m) {
                int row = wm * 64 + m * 16 + (lane & 15);
                int slot = row * 8 + (ksl ^ (row & 7));
                xf[m] = *(const short8*)(As + slot * 16);
            }
#pragma unroll
            for (int nn = 0; nn < 4; ++nn)
#pragma unroll
                for (int m = 0; m < 4; ++m)
                    acc[nn][m] = __builtin_amdgcn_mfma_f32_16x16x32_bf16(wf[nn], xf[m],
                                                                         acc[nn][m], 0, 0, 0);
        }
        __syncthreads();
    }
    const int m_lo = lane & 15, c_hi = lane >> 4;
#pragma unroll
    for (int m = 0; m < 4; ++m) {
        int row = row0 + wm * 64 + m * 16 + m_lo;
        if (row < M) {
            float dv = SCALE ? dis[row] : 1.f;
#pragma unroll
            for (int nn = 0; nn < 4; ++nn) {
                int c0 = wn * 64 + nn * 16 + c_hi * 4;
                float4 bb = *(const float4*)(bias + c0);
                us4 o;
                o[0] = f2b(fmaxf(acc[nn][m][0] + bb.x, 0.f) * dv);
                o[1] = f2b(fmaxf(acc[nn][m][1] + bb.y, 0.f) * dv);
                o[2] = f2b(fmaxf(acc[nn][m][2] + bb.z, 0.f) * dv);
                o[3] = f2b(fmaxf(acc[nn][m][3] + bb.w, 0.f) * dv);
                *(us4*)(Yout + (size_t)row * HID + c0) = o;
            }
        }
    }
}

// ---------------- pooling ----------------
__global__ __launch_bounds__(256) void k_pool(const ushort_t* __restrict__ H,
                                              const int* __restrict__ batch,
                                              float* __restrict__ out, int n) {
    int c = threadIdx.x;
    int n0 = blockIdx.x * 128;
    if (n0 >= n) return;
    int nEnd = min(n0 + 128, n);
    int g = batch[n0];
    float sum = 0.f;
    for (int i = n0; i < nEnd; ++i) {
        int gi = batch[i];
        if (gi != g) {
            atomicAdd(&out[(size_t)g * HID + c], sum);
            sum = 0.f;
            g = gi;
        }
        sum += b2f(H[(size_t)i * HID + c]);
    }
    atomicAdd(&out[(size_t)g * HID + c], sum);
}

__global__ void k_div(float* __restrict__ out, const int* __restrict__ gcnt, int G) {
    int g = blockIdx.x;
    int c = threadIdx.x;
    float d = (float)max(gcnt[g], 1);
    out[(size_t)g * HID + c] /= d;
}

extern "C" void kernel_launch(void* const* d_in, const int* in_sizes, int n_in,
                              void* d_out, int out_size, void* d_ws, size_t ws_size,
                              hipStream_t stream) {
    const float* x = (const float*)d_in[0];
    const float* W1 = (const float*)d_in[1];
    const float* b1 = (const float*)d_in[2];
    const float* W2 = (const float*)d_in[3];
    const float* b2 = (const float*)d_in[4];
    const int* ei = (const int*)d_in[5];
    const int* batch = (const int*)d_in[6];
    float* out = (float*)d_out;

    const int N = in_sizes[6];        // 50000
    const int E = in_sizes[5] / 2;    // 800000
    const int K1 = in_sizes[0] / N;   // 128
    const int G = out_size / HID;     // 500
    (void)n_in; (void)ws_size;

    char* w = (char*)d_ws;
    int* cnt = (int*)(w + 0);                       // 50000 i32
    float* dis = (float*)(w + 200704);              // 50000 f32
    int* off = (int*)(w + 401408);                  // 50001 i32
    int* woff = (int*)(w + 602112);                 // 50000 i32 (working copy)
    int* csr = (int*)(w + 802816);                  // 800000 i32
    int* gcnt = (int*)(w + 4003840);                // 500 i32
    int* bsum = (int*)(w + 4005888);                // 256 i32
    int* boff = (int*)(w + 4006912);                // 256 i32
    ushort_t* Wt1 = (ushort_t*)(w + 4007936);       // 128*256 bf16 pre-swizzled
    ushort_t* Wt2 = (ushort_t*)(w + 4073472);       // 256*256 bf16
    ushort_t* Xd = (ushort_t*)(w + 4204544);        // 50000*128 bf16 (dis*x)
    ushort_t* Z1 = (ushort_t*)(w + 17004544);       // 50000*128 bf16
    ushort_t* H1d = (ushort_t*)(w + 29804544);      // 50000*256 bf16 (dis*relu)
    ushort_t* Z2 = (ushort_t*)(w + 55404544);       // 50000*256 bf16
    ushort_t* H2 = (ushort_t*)(w + 4204544);        // 50000*256 bf16 (aliases Xd+Z1, both dead)

    hipMemsetAsync(cnt, 0, (size_t)N * sizeof(int), stream);
    hipMemsetAsync(out, 0, (size_t)out_size * sizeof(float), stream);

    const int nb = (N + 255) / 256;   // 196
    const int eb = (E + 255) / 256;   // 3125
    k_count<<<eb, 256, 0, stream>>>(ei + E, cnt, E);
    k_gcnt_search<<<(G + 255) / 256, 256, 0, stream>>>(batch, gcnt, N, G);
    k_bsum_dis<<<nb, 256, 0, stream>>>(cnt, bsum, dis, N);
    k_scan_bsum<<<1, 256, 0, stream>>>(bsum, boff, nb);
    k_scan_fin<<<nb, 256, 0, stream>>>(cnt, boff, off, woff, N, E);
    k_fill<<<eb, 256, 0, stream>>>(ei, ei + E, woff, csr, E);

    int rshift = 31 - __builtin_clz((unsigned)(K1 / 8));   // log2(K1/8) = 4
    k_cast<<<(N * K1 / 8 + 255) / 256, 256, 0, stream>>>(x, dis, Xd, N * K1 / 8, rshift);
    k_prep_wt<<<K1, 256, 0, stream>>>(W1, Wt1);
    k_prep_wt<<<HID, 256, 0, stream>>>(W2, Wt2);

    int gblk = (N + 127) / 128;
    // layer 1: aggregate first (128 ch), then GEMM with fused bias+relu+dis
    k_agg<16><<<(N + 3) / 4, 256, 0, stream>>>(Xd, Z1, off, csr, dis, N);
    k_gemm_mfma<128, true><<<gblk, 512, 0, stream>>>(Z1, Wt1, dis, b1, H1d, N);
    // layer 2: aggregate (256 ch), then GEMM with fused bias+relu
    k_agg<32><<<(N + 3) / 4, 256, 0, stream>>>(H1d, Z2, off, csr, dis, N);
    k_gemm_mfma<256, false><<<gblk, 512, 0, stream>>>(Z2, Wt2, dis, b2, H2, N);

    k_pool<<<(N + 127) / 128, 256, 0, stream>>>(H2, batch, out, N);
    k_div<<<G, HID, 0, stream>>>(out, gcnt, G);
}

// Round 6
// 273.918 us; speedup vs baseline: 2.4335x; 1.0465x over previous
//
#include <hip/hip_runtime.h>

#define HID 256
typedef unsigned short ushort_t;
typedef unsigned int uint_t;
typedef __attribute__((ext_vector_type(8))) short short8;
typedef __attribute__((ext_vector_type(4))) float f32x4;
typedef __attribute__((ext_vector_type(4))) unsigned short us4;
typedef __attribute__((ext_vector_type(8))) unsigned short us8;

__device__ __forceinline__ ushort_t f2b(float f) {
    uint_t u = __float_as_uint(f);
    u = u + 0x7fffu + ((u >> 16) & 1u);   // RNE
    return (ushort_t)(u >> 16);
}

// ---------------- degree count (edge-only, 1 edge/thread) ----------------
__global__ __launch_bounds__(256) void k_count(const int* __restrict__ dst,
                                               int* __restrict__ cnt, int E) {
    int i = blockIdx.x * 256 + threadIdx.x;
    if (i < E) atomicAdd(&cnt[dst[i]], 1);
}

// ---------------- graph counts via binary search (batch sorted, no atomics) ----------
__global__ __launch_bounds__(256) void k_gcnt_search(const int* __restrict__ batch,
                                                     int* __restrict__ gcnt, int n, int G) {
    int g = blockIdx.x * 256 + threadIdx.x;
    if (g >= G) return;
    int lo = 0, hi = n;
    while (lo < hi) { int mid = (lo + hi) >> 1; if (batch[mid] < g) lo = mid + 1; else hi = mid; }
    int lb = lo;
    hi = n;
    while (lo < hi) { int mid = (lo + hi) >> 1; if (batch[mid] < g + 1) lo = mid + 1; else hi = mid; }
    gcnt[g] = lo - lb;
}

// ---------------- block sums + dis (fused) ----------------
__global__ __launch_bounds__(256) void k_bsum_dis(const int* __restrict__ cnt,
                                                  int* __restrict__ bsum,
                                                  float* __restrict__ dis, int n) {
    __shared__ int s[256];
    int t = threadIdx.x;
    int i = blockIdx.x * 256 + t;
    int c = (i < n) ? cnt[i] : 0;
    if (i < n) dis[i] = rsqrtf((float)(c + 1));
    s[t] = c;
    __syncthreads();
#pragma unroll
    for (int d = 128; d > 0; d >>= 1) {
        if (t < d) s[t] += s[t + d];
        __syncthreads();
    }
    if (t == 0) bsum[blockIdx.x] = s[0];
}

// exclusive scan of block sums (nb <= 256)
__global__ __launch_bounds__(256) void k_scan_bsum(const int* __restrict__ bsum,
                                                   int* __restrict__ boff, int nb) {
    __shared__ int s[256];
    int t = threadIdx.x;
    int v = (t < nb) ? bsum[t] : 0;
    s[t] = v;
    __syncthreads();
#pragma unroll
    for (int d = 1; d < 256; d <<= 1) {
        int u = (t >= d) ? s[t - d] : 0;
        __syncthreads();
        s[t] += u;
        __syncthreads();
    }
    if (t < nb) boff[t] = s[t] - v;
}

// per-chunk exclusive scan + block offset; writes off AND working copy woff
__global__ __launch_bounds__(256) void k_scan_fin(const int* __restrict__ cnt,
                                                  const int* __restrict__ boff,
                                                  int* __restrict__ off,
                                                  int* __restrict__ woff, int n, int E) {
    __shared__ int s[256];
    int t = threadIdx.x;
    int i = blockIdx.x * 256 + t;
    int v = (i < n) ? cnt[i] : 0;
    s[t] = v;
    __syncthreads();
#pragma unroll
    for (int d = 1; d < 256; d <<= 1) {
        int u = (t >= d) ? s[t - d] : 0;
        __syncthreads();
        s[t] += u;
        __syncthreads();
    }
    if (i < n) {
        int o = boff[blockIdx.x] + s[t] - v;
        off[i] = o;
        woff[i] = o;
    }
    if (blockIdx.x == 0 && t == 0) off[n] = E;
}

// ---------------- CSR fill (by dst); woff doubles as position counter ----------------
__global__ __launch_bounds__(256) void k_fill(const int* __restrict__ src,
                                              const int* __restrict__ dst,
                                              int* __restrict__ woff,
                                              int* __restrict__ csr, int E) {
    int i = blockIdx.x * 256 + threadIdx.x;
    if (i < E) {
        int pos = atomicAdd(&woff[dst[i]], 1);
        csr[pos] = src[i];
    }
}

// ---------------- cast: Xg (grouped [K/32][n][32]) = bf16(dis[row] * x) ----------------
__global__ void k_cast(const float* __restrict__ x, const float* __restrict__ dis,
                       ushort_t* __restrict__ xg, int total8, int rshift, int n) {
    int i = blockIdx.x * blockDim.x + threadIdx.x;
    if (i >= total8) return;
    int r = i >> rshift;                  // row
    int j = i & ((1 << rshift) - 1);      // which us8 within the row
    float dv = dis[r];
    const float4* p = (const float4*)(x + (size_t)i * 8);
    float4 v0 = p[0], v1 = p[1];
    us8 o;
    o[0] = f2b(v0.x * dv); o[1] = f2b(v0.y * dv); o[2] = f2b(v0.z * dv); o[3] = f2b(v0.w * dv);
    o[4] = f2b(v1.x * dv); o[5] = f2b(v1.y * dv); o[6] = f2b(v1.z * dv); o[7] = f2b(v1.w * dv);
    size_t dst = (size_t)(j >> 2) * ((size_t)n * 32) + (size_t)r * 32 + (size_t)(j & 3) * 8;
    *(us8*)(xg + dst) = o;
}

// ---------------- W -> transposed, bf16, K-panel-blocked, PRE-SWIZZLED ----------------
__global__ void k_prep_wt(const float* __restrict__ W, ushort_t* __restrict__ Wt) {
    int kg = blockIdx.x;        // k row of W
    int c = threadIdx.x;        // 0..255 column
    float v = W[(size_t)kg * HID + c];
    int p = kg >> 6;
    int k = kg & 63;
    int byte_ = c * 128 + k * 2;
    int slot = byte_ >> 4;
    int sw = (slot & ~7) | ((slot ^ c) & 7);
    size_t dst_byte = (size_t)p * 32768 + ((size_t)sw << 4) + (byte_ & 15);
    Wt[dst_byte >> 1] = f2b(v);
}

// ---------------- grouped aggregation ----------------
// Yg: grouped [NG][n][32] bf16. Z: row-major [n][NG*32] bf16.
// group = blockIdx.x % NG  (round-robin blockIdx->XCD pins each group to one XCD's L2).
// Quarter-wave (16 lanes = 4 parities x 4 lanes x 16B) per node.
// Z[v] = bf16( dis_v * (Yg[v] + sum_{s in csr[v]} Yg[s]) )
#define ACC8(r)                                                            \
    a0 += __uint_as_float((r).x << 16); a1 += __uint_as_float((r).x & 0xffff0000u); \
    a2 += __uint_as_float((r).y << 16); a3 += __uint_as_float((r).y & 0xffff0000u); \
    a4 += __uint_as_float((r).z << 16); a5 += __uint_as_float((r).z & 0xffff0000u); \
    a6 += __uint_as_float((r).w << 16); a7 += __uint_as_float((r).w & 0xffff0000u);

template <int NG>
__global__ __launch_bounds__(256) void k_agg_g(const ushort_t* __restrict__ Yg,
                                               ushort_t* __restrict__ Z,
                                               const int* __restrict__ off,
                                               const int* __restrict__ csr,
                                               const float* __restrict__ dis, int n) {
    const int LOG = (NG == 8) ? 3 : 2;
    const int g = blockIdx.x & (NG - 1);
    const int chunk = blockIdx.x >> LOG;
    const int q = threadIdx.x >> 4;       // quarter index within block (16 nodes/block)
    const int l16 = threadIdx.x & 15;
    const int v = chunk * 16 + q;
    if (v >= n) return;
    const int par = l16 >> 2;             // 0..3 edge parity
    const int sub = l16 & 3;              // 0..3 -> 8 channels (16B) each
    const ushort_t* Yb = Yg + (size_t)g * ((size_t)n * 32);
    float a0 = 0.f, a1 = 0.f, a2 = 0.f, a3 = 0.f, a4 = 0.f, a5 = 0.f, a6 = 0.f, a7 = 0.f;
    int e = off[v] + par;
    const int end = off[v + 1];
    while (e + 4 < end) {
        int s0 = csr[e], s1 = csr[e + 4];
        uint4 r0 = *(const uint4*)(Yb + (size_t)s0 * 32 + sub * 8);
        uint4 r1 = *(const uint4*)(Yb + (size_t)s1 * 32 + sub * 8);
        ACC8(r0);
        ACC8(r1);
        e += 8;
    }
    if (e < end) {
        int s0 = csr[e];
        uint4 r0 = *(const uint4*)(Yb + (size_t)s0 * 32 + sub * 8);
        ACC8(r0);
    }
    // reduce the 4 parities (stays within the 16-lane quarter)
    a0 += __shfl_xor(a0, 4, 64); a1 += __shfl_xor(a1, 4, 64);
    a2 += __shfl_xor(a2, 4, 64); a3 += __shfl_xor(a3, 4, 64);
    a4 += __shfl_xor(a4, 4, 64); a5 += __shfl_xor(a5, 4, 64);
    a6 += __shfl_xor(a6, 4, 64); a7 += __shfl_xor(a7, 4, 64);
    a0 += __shfl_xor(a0, 8, 64); a1 += __shfl_xor(a1, 8, 64);
    a2 += __shfl_xor(a2, 8, 64); a3 += __shfl_xor(a3, 8, 64);
    a4 += __shfl_xor(a4, 8, 64); a5 += __shfl_xor(a5, 8, 64);
    a6 += __shfl_xor(a6, 8, 64); a7 += __shfl_xor(a7, 8, 64);
    if (par == 0) {
        uint4 r = *(const uint4*)(Yb + (size_t)v * 32 + sub * 8);   // self loop
        ACC8(r);
        float dv = dis[v];
        us8 o;
        o[0] = f2b(a0 * dv); o[1] = f2b(a1 * dv); o[2] = f2b(a2 * dv); o[3] = f2b(a3 * dv);
        o[4] = f2b(a4 * dv); o[5] = f2b(a5 * dv); o[6] = f2b(a6 * dv); o[7] = f2b(a7 * dv);
        *(us8*)(Z + (size_t)v * (NG * 32) + g * 32 + sub * 8) = o;
    }
}

// ---------------- MFMA GEMM: Yout[row][c] = bf16( post( A[row]·W[:,c] + bias[c] ) ) ----
// post = relu, then (SCALE ? *dis[row] : identity). OUTG: write grouped [8][M][32].
template <int K, bool SCALE, bool OUTG>
__global__ __launch_bounds__(512) void k_gemm_mfma(const ushort_t* __restrict__ A,
                                                   const ushort_t* __restrict__ Wt,
                                                   const float* __restrict__ dis,
                                                   const float* __restrict__ bias,
                                                   ushort_t* __restrict__ Yout, int M) {
    __shared__ char lds[49152];
    char* As = lds;            // 128 rows x 64 k bf16, swizzled: 16384 B
    char* Bs = lds + 16384;    // 256 cols x 64 k bf16, swizzled: 32768 B
    const int tid = threadIdx.x;
    const int lane = tid & 63;
    const int w = tid >> 6;
    const int wm = w & 1;
    const int wn = w >> 1;
    const int row0 = blockIdx.x * 128;

    f32x4 acc[4][4];
#pragma unroll
    for (int i = 0; i < 4; ++i)
#pragma unroll
        for (int j = 0; j < 4; ++j) acc[i][j] = (f32x4){0.f, 0.f, 0.f, 0.f};

    for (int k0 = 0; k0 < K; k0 += 64) {
#pragma unroll
        for (int q = 0; q < 2; ++q) {
            int s = q * 512 + tid;
            int r = s >> 3;
            int kseg = (s & 7) ^ (r & 7);
            int row = row0 + r;
            if (row >= M) row = 0;
            const ushort_t* g = A + (size_t)row * K + k0 + kseg * 8;
            __builtin_amdgcn_global_load_lds((const uint_t*)g,
                                             (uint_t*)(As + q * 8192 + w * 1024), 16, 0, 0);
        }
        const ushort_t* gp = Wt + (size_t)(k0 >> 6) * (256 * 64);
#pragma unroll
        for (int q = 0; q < 4; ++q) {
            int s = q * 512 + tid;
            __builtin_amdgcn_global_load_lds((const uint_t*)(gp + (size_t)s * 8),
                                             (uint_t*)(Bs + q * 8192 + w * 1024), 16, 0, 0);
        }
        __syncthreads();
#pragma unroll
        for (int k32 = 0; k32 < 2; ++k32) {
            const int ksl = k32 * 4 + (lane >> 4);
            short8 wf[4], xf[4];
#pragma unroll
            for (int nn = 0; nn < 4; ++nn) {
                int col = wn * 64 + nn * 16 + (lane & 15);
                int slot = col * 8 + (ksl ^ (col & 7));
                wf[nn] = *(const short8*)(Bs + slot * 16);
            }
#pragma unroll
            for (int m = 0; m < 4; ++m) {
                int row = wm * 64 + m * 16 + (lane & 15);
                int slot = row * 8 + (ksl ^ (row & 7));
                xf[m] = *(const short8*)(As + slot * 16);
            }
#pragma unroll
            for (int nn = 0; nn < 4; ++nn)
#pragma unroll
                for (int m = 0; m < 4; ++m)
                    acc[nn][m] = __builtin_amdgcn_mfma_f32_16x16x32_bf16(wf[nn], xf[m],
                                                                         acc[nn][m], 0, 0, 0);
        }
        __syncthreads();
    }
    const int m_lo = lane & 15, c_hi = lane >> 4;
#pragma unroll
    for (int m = 0; m < 4; ++m) {
        int row = row0 + wm * 64 + m * 16 + m_lo;
        if (row < M) {
            float dv = SCALE ? dis[row] : 1.f;
#pragma unroll
            for (int nn = 0; nn < 4; ++nn) {
                int c0 = wn * 64 + nn * 16 + c_hi * 4;
                float4 bb = *(const float4*)(bias + c0);
                us4 o;
                o[0] = f2b(fmaxf(acc[nn][m][0] + bb.x, 0.f) * dv);
                o[1] = f2b(fmaxf(acc[nn][m][1] + bb.y, 0.f) * dv);
                o[2] = f2b(fmaxf(acc[nn][m][2] + bb.z, 0.f) * dv);
                o[3] = f2b(fmaxf(acc[nn][m][3] + bb.w, 0.f) * dv);
                size_t dst = OUTG
                    ? ((size_t)(c0 >> 5) * ((size_t)M * 32) + (size_t)row * 32 + (c0 & 31))
                    : ((size_t)row * HID + c0);
                *(us4*)(Yout + dst) = o;
            }
        }
    }
}

// ---------------- pooling ----------------
__global__ __launch_bounds__(256) void k_pool(const ushort_t* __restrict__ H,
                                              const int* __restrict__ batch,
                                              float* __restrict__ out, int n) {
    int c = threadIdx.x;
    int n0 = blockIdx.x * 128;
    if (n0 >= n) return;
    int nEnd = min(n0 + 128, n);
    int g = batch[n0];
    float sum = 0.f;
    for (int i = n0; i < nEnd; ++i) {
        int gi = batch[i];
        if (gi != g) {
            atomicAdd(&out[(size_t)g * HID + c], sum);
            sum = 0.f;
            g = gi;
        }
        sum += __uint_as_float(((uint_t)H[(size_t)i * HID + c]) << 16);
    }
    atomicAdd(&out[(size_t)g * HID + c], sum);
}

__global__ void k_div(float* __restrict__ out, const int* __restrict__ gcnt, int G) {
    int g = blockIdx.x;
    int c = threadIdx.x;
    float d = (float)max(gcnt[g], 1);
    out[(size_t)g * HID + c] /= d;
}

extern "C" void kernel_launch(void* const* d_in, const int* in_sizes, int n_in,
                              void* d_out, int out_size, void* d_ws, size_t ws_size,
                              hipStream_t stream) {
    const float* x = (const float*)d_in[0];
    const float* W1 = (const float*)d_in[1];
    const float* b1 = (const float*)d_in[2];
    const float* W2 = (const float*)d_in[3];
    const float* b2 = (const float*)d_in[4];
    const int* ei = (const int*)d_in[5];
    const int* batch = (const int*)d_in[6];
    float* out = (float*)d_out;

    const int N = in_sizes[6];        // 50000
    const int E = in_sizes[5] / 2;    // 800000
    const int K1 = in_sizes[0] / N;   // 128
    const int G = out_size / HID;     // 500
    (void)n_in; (void)ws_size;

    char* w = (char*)d_ws;
    int* cnt = (int*)(w + 0);                       // 50000 i32
    float* dis = (float*)(w + 200704);              // 50000 f32
    int* off = (int*)(w + 401408);                  // 50001 i32
    int* woff = (int*)(w + 602112);                 // 50000 i32 (working copy)
    int* csr = (int*)(w + 802816);                  // 800000 i32
    int* gcnt = (int*)(w + 4003840);                // 500 i32
    int* bsum = (int*)(w + 4005888);                // 256 i32
    int* boff = (int*)(w + 4006912);                // 256 i32
    ushort_t* Wt1 = (ushort_t*)(w + 4007936);       // 128*256 bf16 pre-swizzled
    ushort_t* Wt2 = (ushort_t*)(w + 4073472);       // 256*256 bf16
    ushort_t* Xg = (ushort_t*)(w + 4204544);        // grouped [4][N][32] bf16 (dis*x)
    ushort_t* Z1 = (ushort_t*)(w + 17004544);       // [N][128] bf16
    ushort_t* H1g = (ushort_t*)(w + 29804544);      // grouped [8][N][32] bf16
    ushort_t* Z2 = (ushort_t*)(w + 55404544);       // [N][256] bf16
    ushort_t* H2 = (ushort_t*)(w + 4204544);        // [N][256] bf16 (aliases Xg+Z1, both dead)

    hipMemsetAsync(cnt, 0, (size_t)N * sizeof(int), stream);
    hipMemsetAsync(out, 0, (size_t)out_size * sizeof(float), stream);

    const int nb = (N + 255) / 256;   // 196
    const int eb = (E + 255) / 256;   // 3125
    k_count<<<eb, 256, 0, stream>>>(ei + E, cnt, E);
    k_gcnt_search<<<(G + 255) / 256, 256, 0, stream>>>(batch, gcnt, N, G);
    k_bsum_dis<<<nb, 256, 0, stream>>>(cnt, bsum, dis, N);
    k_scan_bsum<<<1, 256, 0, stream>>>(bsum, boff, nb);
    k_scan_fin<<<nb, 256, 0, stream>>>(cnt, boff, off, woff, N, E);
    k_fill<<<eb, 256, 0, stream>>>(ei, ei + E, woff, csr, E);

    int rshift = 31 - __builtin_clz((unsigned)(K1 / 8));   // log2(K1/8) = 4
    k_cast<<<(N * K1 / 8 + 255) / 256, 256, 0, stream>>>(x, dis, Xg, N * K1 / 8, rshift, N);
    k_prep_wt<<<K1, 256, 0, stream>>>(W1, Wt1);
    k_prep_wt<<<HID, 256, 0, stream>>>(W2, Wt2);

    int gblk = (N + 127) / 128;
    const int chunks = (N + 15) / 16;  // 3125
    // layer 1: grouped aggregate (4 groups x 32ch), then GEMM (fused bias+relu+dis, grouped out)
    k_agg_g<4><<<4 * chunks, 256, 0, stream>>>(Xg, Z1, off, csr, dis, N);
    k_gemm_mfma<128, true, true><<<gblk, 512, 0, stream>>>(Z1, Wt1, dis, b1, H1g, N);
    // layer 2: grouped aggregate (8 groups x 32ch), then GEMM (fused bias+relu, row-major out)
    k_agg_g<8><<<8 * chunks, 256, 0, stream>>>(H1g, Z2, off, csr, dis, N);
    k_gemm_mfma<256, false, false><<<gblk, 512, 0, stream>>>(Z2, Wt2, dis, b2, H2, N);

    k_pool<<<(N + 127) / 128, 256, 0, stream>>>(H2, batch, out, N);
    k_div<<<G, HID, 0, stream>>>(out, gcnt, G);
}